// Round 1
// baseline (458.265 us; speedup 1.0000x reference)
//
#include <hip/hip_runtime.h>
#include <hip/hip_bf16.h>
#include <stdint.h>

// non_local_layer: B=8, C=1024, N=48*48=2304, Cb=512. f32 in/out, bf16 MFMA inside.
// R9: port the three bf16 GEMMs (g, attn, y) to a 256x256-tile 8-phase schedule
// (T2 swizzle + T3/T4 counted-vmcnt pipeline + T5 setprio). Staging is REGISTER-based
// (global->reg->ds_write) deliberately: R7 bisected a cross-launch corruption to
// global_load_lds, so it stays banned. The 4-slot reg ring (load at phase p, write at
// p+4) lets the compiler emit exact counted vmcnt from dataflow; the main loop never
// drains vmcnt to 0. wy GEMM keeps the proven 128^2 kernel (fused BN reduction).

typedef __bf16 bf16;
typedef __attribute__((ext_vector_type(8))) __bf16 bf16x8;
typedef __attribute__((ext_vector_type(4))) float f32x4;

__device__ __forceinline__ void wg_barrier()
{
    asm volatile("" ::: "memory");
    __builtin_amdgcn_s_barrier();
    asm volatile("" ::: "memory");
}

// ---------------- 256x256 8-phase GEMM (bt-form, bf16 out) ----------------
// D[m][n] = alpha * sum_k A[m][k]*B[n][k].  8 waves (2M x 4N), per-wave 128x64.
// LDS 128 KiB: dbuf d in {0,1}; within dbuf: A (256x64, 32KB) then B (32KB).
// Tile rows stored 128B/row, chunk s of row r holds global k-chunk s^(r&7) (proven
// swizzle from the 128^2 kernel; SQ_LDS_BANK_CONFLICT was 0).
// Iteration i computes kt 2i (d0, phases 0-3) and 2i+1 (d1, phases 4-7).
// Per phase: 4 (or 12) ds_read_b128 -> ds_write of ring slot (loaded 4 phases ago)
// -> 2 global loads into same slot -> barrier -> lgkmcnt(0) -> setprio(1) 16 MFMA.
__global__ __launch_bounds__(512, 2)
void gemm_bt256(const bf16* __restrict__ Ag, const bf16* __restrict__ Bg,
                bf16* __restrict__ Dg, int K, int N,
                long long sA, long long sB, long long sD, float alpha)
{
    __shared__ __align__(16) char lds[131072];

    const int tid  = threadIdx.x;
    const int lane = tid & 63;
    const int wv   = tid >> 6;     // 8 waves: 2 (M) x 4 (N)
    const int wm   = wv >> 2;      // 0..1
    const int wn   = wv & 3;       // 0..3

    const bf16* Ab = Ag + (long long)blockIdx.z * sA + (long long)blockIdx.y * 256 * K;
    const bf16* Bb = Bg + (long long)blockIdx.z * sB + (long long)blockIdx.x * 256 * K;

    // staging geometry: half-tile = 128 rows x 8 chunks of 16B = 1024 chunks;
    // thread moves chunks ch0=tid (rows 0..63) and ch1=tid+512 (rows 64..127).
    const int r0 = tid >> 3,        c0 = (tid & 7) ^ (r0 & 7);
    const int r1 = (tid + 512) >> 3, c1 = (tid & 7) ^ (r1 & 7);
    auto gofs0 = [&](int half, int kb) { return (half * 128 + r0) * K + kb + c0 * 8; };
    auto gofs1 = [&](int half, int kb) { return (half * 128 + r1) * K + kb + c1 * 8; };

    const int NIT = K >> 7;        // K % 128 == 0 for all call sites (1024, 2304)

    // phase tables (slot = p&3):
    //   loads (iter i): p0..p3 -> kt 2i+2 {B0,B1,A0,A1}; p4..p7 -> kt 2i+3 {B0,B1,A0,A1}
    //   writes:         p0..p3 -> d1 {B0,B1,A0,A1} (kt 2i+1, data from prev iter p4..p7)
    //                   p4..p7 -> d0 {B0,B1,A0,A1} (kt 2i+2, data from this iter p0..p3)
    static constexpr int  srcB[8] = {1, 1, 0, 0, 1, 1, 0, 0};
    static constexpr int  half[8] = {0, 1, 0, 1, 0, 1, 0, 1};
    static constexpr int  kof [8] = {128, 128, 128, 128, 192, 192, 192, 192};
    static constexpr int  wof [8] = {98304, 114688, 65536, 81920, 32768, 49152, 0, 16384};

    f32x4 acc[8][4];
    #pragma unroll
    for (int i = 0; i < 8; ++i)
        #pragma unroll
        for (int j = 0; j < 4; ++j) {
            f32x4 z = {0.f, 0.f, 0.f, 0.f};
            acc[i][j] = z;
        }

    bf16x8 sl[4][2];       // prefetch ring: slot s holds one half-tile (2 chunks)
    bf16x8 bfrag[4][2];    // B fragments, loaded at q==0, live across 4 phases

    // ---- prologue: kt0 -> d0 directly; ring <- kt1 ----
    {
        bf16x8 b0a = *(const bf16x8*)(Bb + gofs0(0, 0));
        bf16x8 b0b = *(const bf16x8*)(Bb + gofs1(0, 0));
        bf16x8 b1a = *(const bf16x8*)(Bb + gofs0(1, 0));
        bf16x8 b1b = *(const bf16x8*)(Bb + gofs1(1, 0));
        bf16x8 a0a = *(const bf16x8*)(Ab + gofs0(0, 0));
        bf16x8 a0b = *(const bf16x8*)(Ab + gofs1(0, 0));
        bf16x8 a1a = *(const bf16x8*)(Ab + gofs0(1, 0));
        bf16x8 a1b = *(const bf16x8*)(Ab + gofs1(1, 0));
        sl[0][0] = *(const bf16x8*)(Bb + gofs0(0, 64));
        sl[0][1] = *(const bf16x8*)(Bb + gofs1(0, 64));
        sl[1][0] = *(const bf16x8*)(Bb + gofs0(1, 64));
        sl[1][1] = *(const bf16x8*)(Bb + gofs1(1, 64));
        sl[2][0] = *(const bf16x8*)(Ab + gofs0(0, 64));
        sl[2][1] = *(const bf16x8*)(Ab + gofs1(0, 64));
        sl[3][0] = *(const bf16x8*)(Ab + gofs0(1, 64));
        sl[3][1] = *(const bf16x8*)(Ab + gofs1(1, 64));
        *(bf16x8*)(lds + 32768 + tid * 16) = b0a;   // d0.B0
        *(bf16x8*)(lds + 40960 + tid * 16) = b0b;
        *(bf16x8*)(lds + 49152 + tid * 16) = b1a;   // d0.B1
        *(bf16x8*)(lds + 57344 + tid * 16) = b1b;
        *(bf16x8*)(lds + 0     + tid * 16) = a0a;   // d0.A0
        *(bf16x8*)(lds + 8192  + tid * 16) = a0b;
        *(bf16x8*)(lds + 16384 + tid * 16) = a1a;   // d0.A1
        *(bf16x8*)(lds + 24576 + tid * 16) = a1b;
        asm volatile("s_waitcnt lgkmcnt(0)" ::: "memory");
        wg_barrier();
        __builtin_amdgcn_sched_barrier(0);
    }

    for (int it = 0; it < NIT; ++it) {
        const int kc = it << 7;
        const bool pf = (it + 1 < NIT);
        #pragma unroll
        for (int p = 0; p < 8; ++p) {
            const int d = p >> 2, q = p & 3, s = p & 3;
            char* dA = lds + d * 65536;
            char* dB = dA + 32768;

            // fragment ds_reads (B once per K-tile, A per phase)
            if (q == 0) {
                #pragma unroll
                for (int j = 0; j < 4; ++j) {
                    int r = wn * 64 + j * 16 + (lane & 15);
                    #pragma unroll
                    for (int ks = 0; ks < 2; ++ks) {
                        int c = ((ks * 4) + (lane >> 4)) ^ (r & 7);
                        bfrag[j][ks] = *(const bf16x8*)(dB + r * 128 + c * 16);
                    }
                }
            }
            bf16x8 af[2][2];
            #pragma unroll
            for (int ii = 0; ii < 2; ++ii) {
                int r = wm * 128 + (q * 2 + ii) * 16 + (lane & 15);
                #pragma unroll
                for (int ks = 0; ks < 2; ++ks) {
                    int c = ((ks * 4) + (lane >> 4)) ^ (r & 7);
                    af[ii][ks] = *(const bf16x8*)(dA + r * 128 + c * 16);
                }
            }

            // ds_write of the half-tile loaded 4 phases ago (compiler emits the
            // exact counted vmcnt for it: 3 newer slots may stay in flight)
            if (p < 4 || pf) {
                *(bf16x8*)(lds + wof[p] + tid * 16)        = sl[s][0];
                *(bf16x8*)(lds + wof[p] + 8192 + tid * 16) = sl[s][1];
            }
            // refill the same ring slot with the half-tile due 4 phases from now
            if (pf) {
                const bf16* src = srcB[p] ? Bb : Ab;
                sl[s][0] = *(const bf16x8*)(src + gofs0(half[p], kc + kof[p]));
                sl[s][1] = *(const bf16x8*)(src + gofs1(half[p], kc + kof[p]));
            }

            wg_barrier();
            asm volatile("s_waitcnt lgkmcnt(0)" ::: "memory");
            __builtin_amdgcn_s_setprio(1);
            #pragma unroll
            for (int ks = 0; ks < 2; ++ks)
                #pragma unroll
                for (int ii = 0; ii < 2; ++ii)
                    #pragma unroll
                    for (int j = 0; j < 4; ++j)
                        acc[q * 2 + ii][j] = __builtin_amdgcn_mfma_f32_16x16x32_bf16(
                            af[ii][ks], bfrag[j][ks], acc[q * 2 + ii][j], 0, 0, 0);
            __builtin_amdgcn_s_setprio(0);
            wg_barrier();
            __builtin_amdgcn_sched_barrier(0);
        }
    }

    // epilogue: verified C/D mapping row=(lane>>4)*4+t, col=lane&15 per 16x16 tile
    const int m_base = blockIdx.y * 256 + wm * 128;
    const int n_base = blockIdx.x * 256 + wn * 64;
    bf16* Db = Dg + (long long)blockIdx.z * sD;
    #pragma unroll
    for (int i = 0; i < 8; ++i)
        #pragma unroll
        for (int j = 0; j < 4; ++j) {
            int col = n_base + j * 16 + (lane & 15);
            #pragma unroll
            for (int t = 0; t < 4; ++t) {
                int rowg = m_base + i * 16 + (lane >> 4) * 4 + t;
                Db[(long long)rowg * N + col] = (bf16)(acc[i][j][t] * alpha);
            }
        }
}

// ---------------- GEMM: 128x128 tile (kept for wy: fused BN reduction) ----------------
template <bool F32OUT, bool BNRED>
__global__ __launch_bounds__(256)
void gemm_bt(const bf16* __restrict__ Ag, const bf16* __restrict__ Bg,
             void* __restrict__ Dg, int K, int N,
             long long sA, long long sB, long long sD, float alpha,
             float* __restrict__ ps, float* __restrict__ pq)
{
    __shared__ char lds[32768];            // A tile 16 KB + B tile 16 KB
    char* ldsA = lds;
    char* ldsB = lds + 16384;

    const int lane = threadIdx.x & 63;
    const int wv   = threadIdx.x >> 6;     // 4 waves, 2x2 arrangement
    const int wm   = wv >> 1;
    const int wn   = wv & 1;

    const bf16* Ab = Ag + (long long)blockIdx.z * sA + (long long)blockIdx.y * 128 * K;
    const bf16* Bb = Bg + (long long)blockIdx.z * sB + (long long)blockIdx.x * 128 * K;

    f32x4 acc[4][4];
    #pragma unroll
    for (int i = 0; i < 4; ++i)
        #pragma unroll
        for (int j = 0; j < 4; ++j) {
            f32x4 z = {0.f, 0.f, 0.f, 0.f};
            acc[i][j] = z;
        }

    for (int k0 = 0; k0 < K; k0 += 64) {
        #pragma unroll
        for (int t = 0; t < 4; ++t) {
            int ch  = (wv * 4 + t) * 64 + lane;   // 0..1023
            int row = ch >> 3;
            int cc  = (ch & 7) ^ (row & 7);
            bf16x8 va = *(const bf16x8*)(Ab + (long long)row * K + k0 + cc * 8);
            bf16x8 vb = *(const bf16x8*)(Bb + (long long)row * K + k0 + cc * 8);
            *(bf16x8*)(ldsA + ch * 16) = va;
            *(bf16x8*)(ldsB + ch * 16) = vb;
        }
        __syncthreads();

        #pragma unroll
        for (int kk = 0; kk < 64; kk += 32) {
            bf16x8 af[4], bfr[4];
            #pragma unroll
            for (int i = 0; i < 4; ++i) {
                int r = wm * 64 + i * 16 + (lane & 15);
                int c = ((kk >> 3) + (lane >> 4)) ^ (r & 7);
                af[i] = *(const bf16x8*)(ldsA + r * 128 + c * 16);
            }
            #pragma unroll
            for (int j = 0; j < 4; ++j) {
                int r = wn * 64 + j * 16 + (lane & 15);
                int c = ((kk >> 3) + (lane >> 4)) ^ (r & 7);
                bfr[j] = *(const bf16x8*)(ldsB + r * 128 + c * 16);
            }
            #pragma unroll
            for (int i = 0; i < 4; ++i)
                #pragma unroll
                for (int j = 0; j < 4; ++j)
                    acc[i][j] = __builtin_amdgcn_mfma_f32_16x16x32_bf16(af[i], bfr[j], acc[i][j], 0, 0, 0);
        }
        __syncthreads();
    }

    float* bs = (float*)lds;               // [128] per-channel sum
    float* bq = (float*)(lds + 512);       // [128] per-channel sumsq
    if (BNRED) {
        if (threadIdx.x < 128) { bs[threadIdx.x] = 0.f; bq[threadIdx.x] = 0.f; }
        __syncthreads();
    }

    const int m_base = blockIdx.y * 128 + wm * 64;
    const int n_base = blockIdx.x * 128 + wn * 64;
    float s_it[4][4], q_it[4][4];
    #pragma unroll
    for (int i = 0; i < 4; ++i) {
        #pragma unroll
        for (int t = 0; t < 4; ++t) { s_it[i][t] = 0.f; q_it[i][t] = 0.f; }
    }
    #pragma unroll
    for (int i = 0; i < 4; ++i) {
        #pragma unroll
        for (int j = 0; j < 4; ++j) {
            int col = n_base + j * 16 + (lane & 15);
            #pragma unroll
            for (int t = 0; t < 4; ++t) {
                int rowg = m_base + i * 16 + (lane >> 4) * 4 + t;
                float v = acc[i][j][t] * alpha;
                if (F32OUT) ((float*)Dg)[(long long)blockIdx.z * sD + (long long)rowg * N + col] = v;
                else        ((bf16*)Dg)[(long long)blockIdx.z * sD + (long long)rowg * N + col] = (bf16)v;
                if (BNRED) { s_it[i][t] += v; q_it[i][t] += v * v; }
            }
        }
    }

    if (BNRED) {
        #pragma unroll
        for (int i = 0; i < 4; ++i) {
            #pragma unroll
            for (int t = 0; t < 4; ++t) {
                float s = s_it[i][t], q = q_it[i][t];
                #pragma unroll
                for (int m = 1; m < 16; m <<= 1) {
                    s += __shfl_xor(s, m);
                    q += __shfl_xor(q, m);
                }
                if ((lane & 15) == 0) {
                    int cl = wm * 64 + i * 16 + (lane >> 4) * 4 + t;   // 0..127
                    atomicAdd(&bs[cl], s);
                    atomicAdd(&bq[cl], q);
                }
            }
        }
        __syncthreads();
        if (threadIdx.x < 128) {
            int cg = blockIdx.y * 128 + threadIdx.x;
            atomicAdd(&ps[cg], bs[threadIdx.x]);
            atomicAdd(&pq[cg], bq[threadIdx.x]);
        }
    }
}

// ---------------- f32 -> bf16 bulk convert (weights) ----------------
__global__ __launch_bounds__(256)
void f32_to_bf16(const float* __restrict__ in, bf16* __restrict__ out, int n)
{
    int idx = (blockIdx.x * 256 + threadIdx.x) * 4;
    if (idx < n) {
        float4 v = *(const float4*)(in + idx);
        out[idx + 0] = (bf16)v.x;
        out[idx + 1] = (bf16)v.y;
        out[idx + 2] = (bf16)v.z;
        out[idx + 3] = (bf16)v.w;
    }
}

// ---------------- zero-init BN accumulators (ws is poisoned 0xAA every launch) ----------------
__global__ __launch_bounds__(256)
void zero_f32(float* __restrict__ p)
{
    p[blockIdx.x * 256 + threadIdx.x] = 0.f;
}

// ---------------- batched transpose x[z][C][N] (f32) -> xT[z][N][C] (bf16) ----------------
__global__ __launch_bounds__(256)
void transpose_f32_bf16(const float* __restrict__ x, bf16* __restrict__ xT)
{
    __shared__ bf16 tile[32][33];
    const float* xb = x + (long long)blockIdx.z * 1024 * 2304;
    bf16* xo = xT + (long long)blockIdx.z * 2304 * 1024;
    const int n0 = blockIdx.x * 32;
    const int c0 = blockIdx.y * 32;
    const int tx = threadIdx.x, ty = threadIdx.y;   // (32, 8)
    #pragma unroll
    for (int i = 0; i < 32; i += 8)
        tile[ty + i][tx] = (bf16)xb[(long long)(c0 + ty + i) * 2304 + n0 + tx];
    __syncthreads();
    #pragma unroll
    for (int i = 0; i < 32; i += 8)
        xo[(long long)(n0 + ty + i) * 1024 + c0 + tx] = tile[tx][ty + i];
}

// ---------------- register-resident row softmax (N=2304), one block per row ----------------
__global__ __launch_bounds__(256)
void softmax_rows(bf16* __restrict__ S)
{
    bf16* p = S + (long long)blockIdx.x * 2304;
    const int t = threadIdx.x;
    __shared__ float red[256];

    bf16x8 v8 = *(const bf16x8*)(p + t * 8);
    float vt = (float)p[2048 + t];
    float f[8];
    float mx = vt;
    #pragma unroll
    for (int i = 0; i < 8; ++i) { f[i] = (float)v8[i]; mx = fmaxf(mx, f[i]); }

    red[t] = mx; __syncthreads();
    for (int s = 128; s > 0; s >>= 1) { if (t < s) red[t] = fmaxf(red[t], red[t + s]); __syncthreads(); }
    mx = red[0];
    __syncthreads();

    float sum = 0.f;
    #pragma unroll
    for (int i = 0; i < 8; ++i) { f[i] = __expf(f[i] - mx); sum += f[i]; }
    vt = __expf(vt - mx); sum += vt;

    red[t] = sum; __syncthreads();
    for (int s = 128; s > 0; s >>= 1) { if (t < s) red[t] += red[t + s]; __syncthreads(); }
    float inv = 1.0f / red[0];

    bf16x8 o;
    #pragma unroll
    for (int i = 0; i < 8; ++i) o[i] = (bf16)(f[i] * inv);
    *(bf16x8*)(p + t * 8) = o;
    p[2048 + t] = (bf16)(vt * inv);
}

// ---------------- BN finalize: psum/pqsm already summed over all batches ----------------
__global__ __launch_bounds__(256)
void bn_finalize(const float* __restrict__ ps, const float* __restrict__ pq,
                 float* __restrict__ mean, float* __restrict__ istd)
{
    int c = blockIdx.x * 256 + threadIdx.x;   // grid 4 x 256 = 1024
    float mu = ps[c] / 18432.0f;
    mean[c] = mu;
    istd[c] = rsqrtf(pq[c] / 18432.0f - mu * mu + 1e-5f);
}

// ---------------- BN apply + residual, all f32, in place on wy(=d_out) ----------------
__global__ __launch_bounds__(256)
void bn_apply(const float* __restrict__ wy, const float* __restrict__ x,
              const float* __restrict__ gamma, const float* __restrict__ beta,
              const float* __restrict__ mean, const float* __restrict__ istd,
              float* __restrict__ z)
{
    long long idx = ((long long)blockIdx.x * 256 + threadIdx.x) * 4;
    int c = (int)((idx / 2304) & 1023);    // layout [B][C][N], N divisible by 4
    float sc = gamma[c] * istd[c];
    float sh = beta[c] - mean[c] * sc;
    float4 w  = *(const float4*)(wy + idx);
    float4 xv = *(const float4*)(x + idx);
    float4 o;
    o.x = w.x * sc + sh + xv.x;
    o.y = w.y * sc + sh + xv.y;
    o.z = w.z * sc + sh + xv.z;
    o.w = w.w * sc + sh + xv.w;
    *(float4*)(z + idx) = o;
}

extern "C" void kernel_launch(void* const* d_in, const int* in_sizes, int n_in,
                              void* d_out, int out_size, void* d_ws, size_t ws_size,
                              hipStream_t stream)
{
    const float* x     = (const float*)d_in[0];
    const float* Wg    = (const float*)d_in[1];
    const float* Wz    = (const float*)d_in[2];
    const float* gamma = (const float*)d_in[3];
    const float* beta  = (const float*)d_in[4];
    float* zo = (float*)d_out;             // f32 output; also serves as the wy buffer

    const int B = 8, C = 1024, Cb = 512, N = 2304;

    // ws-adaptive batch chunking: BC in {8,4,2,1}, largest whose footprint fits.
    const size_t fixedB = ((size_t)Cb * C * 2) * 2 + (size_t)C * 4 * 4 + 4096;
    const size_t perB   = ((size_t)N * C + (size_t)Cb * N + (size_t)N * N + (size_t)N * Cb) * 2 + 1024;
    int BC = 8;
    while (BC > 1 && fixedB + perB * (size_t)BC > ws_size) BC >>= 1;

    char* p = (char*)d_ws;
    auto alloc = [&](size_t bytes) { char* r = p; p += (bytes + 255) & ~(size_t)255; return r; };
    bf16*  Wgb  = (bf16*)alloc((size_t)Cb * C * 2);
    bf16*  Wzb  = (bf16*)alloc((size_t)C * Cb * 2);
    float* psum = (float*)alloc((size_t)C * 4);   // contiguous with pqsm (both 4 KB)
    float* pqsm = (float*)alloc((size_t)C * 4);
    float* mean = (float*)alloc((size_t)C * 4);
    float* istd = (float*)alloc((size_t)C * 4);
    bf16*  xT   = (bf16*)alloc((size_t)BC * N * C * 2);
    bf16*  g    = (bf16*)alloc((size_t)BC * Cb * N * 2);
    bf16*  attn = (bf16*)alloc((size_t)BC * N * N * 2);
    bf16*  yT   = (bf16*)alloc((size_t)BC * N * Cb * 2);

    // 0) weights f32 -> bf16; zero BN accumulators (psum+pqsm contiguous, 2048 floats)
    f32_to_bf16<<<dim3((Cb * C) / (256 * 4)), 256, 0, stream>>>(Wg, Wgb, Cb * C);
    f32_to_bf16<<<dim3((C * Cb) / (256 * 4)), 256, 0, stream>>>(Wz, Wzb, C * Cb);
    zero_f32<<<dim3(8), 256, 0, stream>>>(psum);

    for (int cs = 0; cs < B; cs += BC) {
        const float* xc = x + (long long)cs * C * N;
        float* wyc = zo + (long long)cs * C * N;

        // xT[z][n][c] = x[cs+z][c][n] (bf16)
        transpose_f32_bf16<<<dim3(N / 32, C / 32, BC), dim3(32, 8), 0, stream>>>(xc, xT);

        // g[z][d][n] = sum_c Wgb[d][c] * xT[z][n][c]   (M=512, N=2304, K=1024)
        gemm_bt256<<<dim3(N / 256, Cb / 256, BC), 512, 0, stream>>>(
            Wgb, xT, g, C, N, 0, (long long)N * C, (long long)Cb * N, 1.0f);

        // attn[z][n][m] = sum_c xT[z][n][c]*xT[z][m][c] / 2304  (M=N=2304, K=1024)
        gemm_bt256<<<dim3(N / 256, N / 256, BC), 512, 0, stream>>>(
            xT, xT, attn, C, N, (long long)N * C, (long long)N * C, (long long)N * N,
            1.0f / 2304.0f);

        // row softmax, one read one write
        softmax_rows<<<dim3(BC * N), 256, 0, stream>>>(attn);

        // yT[z][n][d] = sum_m attn[z][n][m] * g[z][d][m]  (M=2304, N=512, K=2304)
        gemm_bt256<<<dim3(Cb / 256, N / 256, BC), 512, 0, stream>>>(
            attn, g, yT, N, Cb, (long long)N * N, (long long)Cb * N, (long long)N * Cb, 1.0f);

        // wy[cs+z][c][n] = sum_d Wzb[c][d] * yT[z][n][d]  (M=1024, N=2304, K=512)
        // -> f32 into d_out, with fused BN sum/sumsq accumulation
        gemm_bt<true, true><<<dim3(N / 128, C / 128, BC), 256, 0, stream>>>(
            Wzb, yT, wyc, Cb, N, 0, (long long)N * Cb, (long long)C * N, 1.0f, psum, pqsm);
    }

    // BN: finalize -> apply (+residual)
    bn_finalize<<<dim3(C / 256), 256, 0, stream>>>(psum, pqsm, mean, istd);
    bn_apply<<<dim3((B * C * N) / (256 * 4)), 256, 0, stream>>>(zo, x, gamma, beta, mean, istd, zo);
}

// Round 2
// 436.002 us; speedup vs baseline: 1.0511x; 1.0511x over previous
//
#include <hip/hip_runtime.h>
#include <hip/hip_bf16.h>
#include <stdint.h>

// non_local_layer: B=8, C=1024, N=48*48=2304, Cb=512. f32 in/out, bf16 MFMA inside.
// R10: revert R9's 256^2 8-phase (1 block/CU -> grid tail + 56%-idle g/y grids; neutral
// on attn, net regression). New lever is algebraic: attn S = xT.xT^T is SYMMETRIC and
// bit-exact under mirroring (same dot, same k-order). gemm_sym computes only the 171
// upper-triangle 128^2 blocks per z (of 324) and writes off-diagonal tiles twice via an
// LDS-staged transpose (pad-136 rows -> 16B-aligned coalesced bf16x8 readout).
// Diagonal blocks skip B staging (A==B). Everything else: R8-proven kernels.

typedef __bf16 bf16;
typedef __attribute__((ext_vector_type(8))) __bf16 bf16x8;
typedef __attribute__((ext_vector_type(4))) float f32x4;

// ---------------- GEMM: 128x128 tile, BK=64, 4 waves x (4x4) 16x16x32 MFMA ----------------
// bt-form: D[m][n] = sum_k A[m][k]*B[n][k]; per-z strides sA/sB/sD; D ld=N; alpha scale.
// LDS: 128 rows x 8 chunks of 16B; chunk (row,s) holds global k-chunk s^(row&7).
// BNRED: accumulate sum/sumsq of D over columns (n) per row (channel) into ps/pq.
template <bool F32OUT, bool BNRED>
__global__ __launch_bounds__(256)
void gemm_bt(const bf16* __restrict__ Ag, const bf16* __restrict__ Bg,
             void* __restrict__ Dg, int K, int N,
             long long sA, long long sB, long long sD, float alpha,
             float* __restrict__ ps, float* __restrict__ pq)
{
    __shared__ char lds[32768];            // A tile 16 KB + B tile 16 KB
    char* ldsA = lds;
    char* ldsB = lds + 16384;

    const int lane = threadIdx.x & 63;
    const int wv   = threadIdx.x >> 6;     // 4 waves, 2x2 arrangement
    const int wm   = wv >> 1;
    const int wn   = wv & 1;

    const bf16* Ab = Ag + (long long)blockIdx.z * sA + (long long)blockIdx.y * 128 * K;
    const bf16* Bb = Bg + (long long)blockIdx.z * sB + (long long)blockIdx.x * 128 * K;

    f32x4 acc[4][4];
    #pragma unroll
    for (int i = 0; i < 4; ++i)
        #pragma unroll
        for (int j = 0; j < 4; ++j) {
            f32x4 z = {0.f, 0.f, 0.f, 0.f};
            acc[i][j] = z;
        }

    for (int k0 = 0; k0 < K; k0 += 64) {
        #pragma unroll
        for (int t = 0; t < 4; ++t) {
            int ch  = (wv * 4 + t) * 64 + lane;   // 0..1023
            int row = ch >> 3;
            int cc  = (ch & 7) ^ (row & 7);
            bf16x8 va = *(const bf16x8*)(Ab + (long long)row * K + k0 + cc * 8);
            bf16x8 vb = *(const bf16x8*)(Bb + (long long)row * K + k0 + cc * 8);
            *(bf16x8*)(ldsA + ch * 16) = va;
            *(bf16x8*)(ldsB + ch * 16) = vb;
        }
        __syncthreads();

        #pragma unroll
        for (int kk = 0; kk < 64; kk += 32) {
            bf16x8 af[4], bfr[4];
            #pragma unroll
            for (int i = 0; i < 4; ++i) {
                int r = wm * 64 + i * 16 + (lane & 15);
                int c = ((kk >> 3) + (lane >> 4)) ^ (r & 7);
                af[i] = *(const bf16x8*)(ldsA + r * 128 + c * 16);
            }
            #pragma unroll
            for (int j = 0; j < 4; ++j) {
                int r = wn * 64 + j * 16 + (lane & 15);
                int c = ((kk >> 3) + (lane >> 4)) ^ (r & 7);
                bfr[j] = *(const bf16x8*)(ldsB + r * 128 + c * 16);
            }
            #pragma unroll
            for (int i = 0; i < 4; ++i)
                #pragma unroll
                for (int j = 0; j < 4; ++j)
                    acc[i][j] = __builtin_amdgcn_mfma_f32_16x16x32_bf16(af[i], bfr[j], acc[i][j], 0, 0, 0);
        }
        __syncthreads();
    }

    float* bs = (float*)lds;               // [128] per-channel sum
    float* bq = (float*)(lds + 512);       // [128] per-channel sumsq
    if (BNRED) {
        if (threadIdx.x < 128) { bs[threadIdx.x] = 0.f; bq[threadIdx.x] = 0.f; }
        __syncthreads();
    }

    const int m_base = blockIdx.y * 128 + wm * 64;
    const int n_base = blockIdx.x * 128 + wn * 64;
    float s_it[4][4], q_it[4][4];
    #pragma unroll
    for (int i = 0; i < 4; ++i) {
        #pragma unroll
        for (int t = 0; t < 4; ++t) { s_it[i][t] = 0.f; q_it[i][t] = 0.f; }
    }
    #pragma unroll
    for (int i = 0; i < 4; ++i) {
        #pragma unroll
        for (int j = 0; j < 4; ++j) {
            int col = n_base + j * 16 + (lane & 15);
            #pragma unroll
            for (int t = 0; t < 4; ++t) {
                int rowg = m_base + i * 16 + (lane >> 4) * 4 + t;
                float v = acc[i][j][t] * alpha;
                if (F32OUT) ((float*)Dg)[(long long)blockIdx.z * sD + (long long)rowg * N + col] = v;
                else        ((bf16*)Dg)[(long long)blockIdx.z * sD + (long long)rowg * N + col] = (bf16)v;
                if (BNRED) { s_it[i][t] += v; q_it[i][t] += v * v; }
            }
        }
    }

    if (BNRED) {
        #pragma unroll
        for (int i = 0; i < 4; ++i) {
            #pragma unroll
            for (int t = 0; t < 4; ++t) {
                float s = s_it[i][t], q = q_it[i][t];
                #pragma unroll
                for (int m = 1; m < 16; m <<= 1) {
                    s += __shfl_xor(s, m);
                    q += __shfl_xor(q, m);
                }
                if ((lane & 15) == 0) {
                    int cl = wm * 64 + i * 16 + (lane >> 4) * 4 + t;   // 0..127
                    atomicAdd(&bs[cl], s);
                    atomicAdd(&bq[cl], q);
                }
            }
        }
        __syncthreads();
        if (threadIdx.x < 128) {
            int cg = blockIdx.y * 128 + threadIdx.x;
            atomicAdd(&ps[cg], bs[threadIdx.x]);
            atomicAdd(&pq[cg], bq[threadIdx.x]);
        }
    }
}

// ---------------- symmetric GEMM: D = alpha * X X^T, 128x128 tiles, upper-tri only ----------------
// Same inner loop as gemm_bt. Block (bi=blockIdx.y, bj=blockIdx.x): live iff bj >= bi.
// Off-diagonal: mirror the tile to (bj,bi) via LDS transpose (rows padded to 136 bf16
// so transposed rows stay 16B-aligned for bf16x8 readout). Diagonal: skip B staging.
__global__ __launch_bounds__(256)
void gemm_sym(const bf16* __restrict__ Xg, bf16* __restrict__ Dg,
              int K, int N, long long sX, long long sD, float alpha)
{
    const int bi = blockIdx.y, bj = blockIdx.x;
    if (bj < bi) return;                   // upper triangle only (incl. diagonal)
    const bool mir  = (bj > bi);
    const bool diag = (bj == bi);

    __shared__ __align__(16) char lds[34816];   // GEMM: A 16K + B 16K; epilogue: 128x136 bf16
    char* ldsA = lds;
    char* ldsB = diag ? lds : (lds + 16384);

    const int lane = threadIdx.x & 63;
    const int wv   = threadIdx.x >> 6;
    const int wm   = wv >> 1;
    const int wn   = wv & 1;

    const bf16* Ab = Xg + (long long)blockIdx.z * sX + (long long)bi * 128 * K;
    const bf16* Bb = Xg + (long long)blockIdx.z * sX + (long long)bj * 128 * K;

    f32x4 acc[4][4];
    #pragma unroll
    for (int i = 0; i < 4; ++i)
        #pragma unroll
        for (int j = 0; j < 4; ++j) {
            f32x4 z = {0.f, 0.f, 0.f, 0.f};
            acc[i][j] = z;
        }

    for (int k0 = 0; k0 < K; k0 += 64) {
        #pragma unroll
        for (int t = 0; t < 4; ++t) {
            int ch  = (wv * 4 + t) * 64 + lane;   // 0..1023
            int row = ch >> 3;
            int cc  = (ch & 7) ^ (row & 7);
            bf16x8 va = *(const bf16x8*)(Ab + (long long)row * K + k0 + cc * 8);
            *(bf16x8*)(ldsA + ch * 16) = va;
            if (!diag) {
                bf16x8 vb = *(const bf16x8*)(Bb + (long long)row * K + k0 + cc * 8);
                *(bf16x8*)(ldsB + ch * 16) = vb;
            }
        }
        __syncthreads();

        #pragma unroll
        for (int kk = 0; kk < 64; kk += 32) {
            bf16x8 af[4], bfr[4];
            #pragma unroll
            for (int i = 0; i < 4; ++i) {
                int r = wm * 64 + i * 16 + (lane & 15);
                int c = ((kk >> 3) + (lane >> 4)) ^ (r & 7);
                af[i] = *(const bf16x8*)(ldsA + r * 128 + c * 16);
            }
            #pragma unroll
            for (int j = 0; j < 4; ++j) {
                int r = wn * 64 + j * 16 + (lane & 15);
                int c = ((kk >> 3) + (lane >> 4)) ^ (r & 7);
                bfr[j] = *(const bf16x8*)(ldsB + r * 128 + c * 16);
            }
            #pragma unroll
            for (int i = 0; i < 4; ++i)
                #pragma unroll
                for (int j = 0; j < 4; ++j)
                    acc[i][j] = __builtin_amdgcn_mfma_f32_16x16x32_bf16(af[i], bfr[j], acc[i][j], 0, 0, 0);
        }
        __syncthreads();
    }

    bf16* Db = Dg + (long long)blockIdx.z * sD;
    bf16 (*tr)[136] = (bf16(*)[136])lds;   // k-loop ended with a barrier; LDS free

    #pragma unroll
    for (int i = 0; i < 4; ++i) {
        #pragma unroll
        for (int j = 0; j < 4; ++j) {
            int c_loc = wn * 64 + j * 16 + (lane & 15);
            int col   = bj * 128 + c_loc;
            #pragma unroll
            for (int t = 0; t < 4; ++t) {
                int r_loc = wm * 64 + i * 16 + (lane >> 4) * 4 + t;
                float v = acc[i][j][t] * alpha;
                Db[(long long)(bi * 128 + r_loc) * N + col] = (bf16)v;
                if (mir) tr[c_loc][r_loc] = (bf16)v;
            }
        }
    }

    if (mir) {
        __syncthreads();
        // 256 threads x 64 bf16: thread (cc=tid>>1, hf=tid&1) copies half a transposed row.
        const int cc = threadIdx.x >> 1, hf = threadIdx.x & 1;
        const bf16* src = &tr[cc][hf * 64];
        bf16* dst = Db + (long long)(bj * 128 + cc) * N + bi * 128 + hf * 64;
        #pragma unroll
        for (int j2 = 0; j2 < 8; ++j2)
            *(bf16x8*)(dst + j2 * 8) = *(const bf16x8*)(src + j2 * 8);
    }
}

// ---------------- f32 -> bf16 bulk convert (weights) ----------------
__global__ __launch_bounds__(256)
void f32_to_bf16(const float* __restrict__ in, bf16* __restrict__ out, int n)
{
    int idx = (blockIdx.x * 256 + threadIdx.x) * 4;
    if (idx < n) {
        float4 v = *(const float4*)(in + idx);
        out[idx + 0] = (bf16)v.x;
        out[idx + 1] = (bf16)v.y;
        out[idx + 2] = (bf16)v.z;
        out[idx + 3] = (bf16)v.w;
    }
}

// ---------------- zero-init BN accumulators (ws is poisoned 0xAA every launch) ----------------
__global__ __launch_bounds__(256)
void zero_f32(float* __restrict__ p)
{
    p[blockIdx.x * 256 + threadIdx.x] = 0.f;
}

// ---------------- batched transpose x[z][C][N] (f32) -> xT[z][N][C] (bf16) ----------------
__global__ __launch_bounds__(256)
void transpose_f32_bf16(const float* __restrict__ x, bf16* __restrict__ xT)
{
    __shared__ bf16 tile[32][33];
    const float* xb = x + (long long)blockIdx.z * 1024 * 2304;
    bf16* xo = xT + (long long)blockIdx.z * 2304 * 1024;
    const int n0 = blockIdx.x * 32;
    const int c0 = blockIdx.y * 32;
    const int tx = threadIdx.x, ty = threadIdx.y;   // (32, 8)
    #pragma unroll
    for (int i = 0; i < 32; i += 8)
        tile[ty + i][tx] = (bf16)xb[(long long)(c0 + ty + i) * 2304 + n0 + tx];
    __syncthreads();
    #pragma unroll
    for (int i = 0; i < 32; i += 8)
        xo[(long long)(n0 + ty + i) * 1024 + c0 + tx] = tile[tx][ty + i];
}

// ---------------- register-resident row softmax (N=2304), one block per row ----------------
__global__ __launch_bounds__(256)
void softmax_rows(bf16* __restrict__ S)
{
    bf16* p = S + (long long)blockIdx.x * 2304;
    const int t = threadIdx.x;
    __shared__ float red[256];

    bf16x8 v8 = *(const bf16x8*)(p + t * 8);
    float vt = (float)p[2048 + t];
    float f[8];
    float mx = vt;
    #pragma unroll
    for (int i = 0; i < 8; ++i) { f[i] = (float)v8[i]; mx = fmaxf(mx, f[i]); }

    red[t] = mx; __syncthreads();
    for (int s = 128; s > 0; s >>= 1) { if (t < s) red[t] = fmaxf(red[t], red[t + s]); __syncthreads(); }
    mx = red[0];
    __syncthreads();

    float sum = 0.f;
    #pragma unroll
    for (int i = 0; i < 8; ++i) { f[i] = __expf(f[i] - mx); sum += f[i]; }
    vt = __expf(vt - mx); sum += vt;

    red[t] = sum; __syncthreads();
    for (int s = 128; s > 0; s >>= 1) { if (t < s) red[t] += red[t + s]; __syncthreads(); }
    float inv = 1.0f / red[0];

    bf16x8 o;
    #pragma unroll
    for (int i = 0; i < 8; ++i) o[i] = (bf16)(f[i] * inv);
    *(bf16x8*)(p + t * 8) = o;
    p[2048 + t] = (bf16)(vt * inv);
}

// ---------------- BN finalize: psum/pqsm already summed over all batches ----------------
__global__ __launch_bounds__(256)
void bn_finalize(const float* __restrict__ ps, const float* __restrict__ pq,
                 float* __restrict__ mean, float* __restrict__ istd)
{
    int c = blockIdx.x * 256 + threadIdx.x;   // grid 4 x 256 = 1024
    float mu = ps[c] / 18432.0f;
    mean[c] = mu;
    istd[c] = rsqrtf(pq[c] / 18432.0f - mu * mu + 1e-5f);
}

// ---------------- BN apply + residual, all f32, in place on wy(=d_out) ----------------
__global__ __launch_bounds__(256)
void bn_apply(const float* __restrict__ wy, const float* __restrict__ x,
              const float* __restrict__ gamma, const float* __restrict__ beta,
              const float* __restrict__ mean, const float* __restrict__ istd,
              float* __restrict__ z)
{
    long long idx = ((long long)blockIdx.x * 256 + threadIdx.x) * 4;
    int c = (int)((idx / 2304) & 1023);    // layout [B][C][N], N divisible by 4
    float sc = gamma[c] * istd[c];
    float sh = beta[c] - mean[c] * sc;
    float4 w  = *(const float4*)(wy + idx);
    float4 xv = *(const float4*)(x + idx);
    float4 o;
    o.x = w.x * sc + sh + xv.x;
    o.y = w.y * sc + sh + xv.y;
    o.z = w.z * sc + sh + xv.z;
    o.w = w.w * sc + sh + xv.w;
    *(float4*)(z + idx) = o;
}

extern "C" void kernel_launch(void* const* d_in, const int* in_sizes, int n_in,
                              void* d_out, int out_size, void* d_ws, size_t ws_size,
                              hipStream_t stream)
{
    const float* x     = (const float*)d_in[0];
    const float* Wg    = (const float*)d_in[1];
    const float* Wz    = (const float*)d_in[2];
    const float* gamma = (const float*)d_in[3];
    const float* beta  = (const float*)d_in[4];
    float* zo = (float*)d_out;             // f32 output; also serves as the wy buffer

    const int B = 8, C = 1024, Cb = 512, N = 2304;

    // ws-adaptive batch chunking: BC in {8,4,2,1}, largest whose footprint fits.
    const size_t fixedB = ((size_t)Cb * C * 2) * 2 + (size_t)C * 4 * 4 + 4096;
    const size_t perB   = ((size_t)N * C + (size_t)Cb * N + (size_t)N * N + (size_t)N * Cb) * 2 + 1024;
    int BC = 8;
    while (BC > 1 && fixedB + perB * (size_t)BC > ws_size) BC >>= 1;

    char* p = (char*)d_ws;
    auto alloc = [&](size_t bytes) { char* r = p; p += (bytes + 255) & ~(size_t)255; return r; };
    bf16*  Wgb  = (bf16*)alloc((size_t)Cb * C * 2);
    bf16*  Wzb  = (bf16*)alloc((size_t)C * Cb * 2);
    float* psum = (float*)alloc((size_t)C * 4);   // contiguous with pqsm (both 4 KB)
    float* pqsm = (float*)alloc((size_t)C * 4);
    float* mean = (float*)alloc((size_t)C * 4);
    float* istd = (float*)alloc((size_t)C * 4);
    bf16*  xT   = (bf16*)alloc((size_t)BC * N * C * 2);
    bf16*  g    = (bf16*)alloc((size_t)BC * Cb * N * 2);
    bf16*  attn = (bf16*)alloc((size_t)BC * N * N * 2);
    bf16*  yT   = (bf16*)alloc((size_t)BC * N * Cb * 2);

    // 0) weights f32 -> bf16; zero BN accumulators (psum+pqsm contiguous, 2048 floats)
    f32_to_bf16<<<dim3((Cb * C) / (256 * 4)), 256, 0, stream>>>(Wg, Wgb, Cb * C);
    f32_to_bf16<<<dim3((C * Cb) / (256 * 4)), 256, 0, stream>>>(Wz, Wzb, C * Cb);
    zero_f32<<<dim3(8), 256, 0, stream>>>(psum);

    for (int cs = 0; cs < B; cs += BC) {
        const float* xc = x + (long long)cs * C * N;
        float* wyc = zo + (long long)cs * C * N;

        // xT[z][n][c] = x[cs+z][c][n] (bf16)
        transpose_f32_bf16<<<dim3(N / 32, C / 32, BC), dim3(32, 8), 0, stream>>>(xc, xT);

        // g[z][d][n] = sum_c Wgb[d][c] * xT[z][n][c]   (M=512, N=2304, K=1024)
        gemm_bt<false, false><<<dim3(N / 128, Cb / 128, BC), 256, 0, stream>>>(
            Wgb, xT, g, C, N, 0, (long long)N * C, (long long)Cb * N, 1.0f, nullptr, nullptr);

        // attn[z][n][m] = sum_c xT[z][n][c]*xT[z][m][c] / 2304  (M=N=2304, K=1024)
        // symmetric: upper-triangle blocks only, mirrored via LDS transpose
        gemm_sym<<<dim3(N / 128, N / 128, BC), 256, 0, stream>>>(
            xT, attn, C, N, (long long)N * C, (long long)N * N, 1.0f / 2304.0f);

        // row softmax, one read one write
        softmax_rows<<<dim3(BC * N), 256, 0, stream>>>(attn);

        // yT[z][n][d] = sum_m attn[z][n][m] * g[z][d][m]  (M=2304, N=512, K=2304)
        gemm_bt<false, false><<<dim3(Cb / 128, N / 128, BC), 256, 0, stream>>>(
            attn, g, yT, N, Cb, (long long)N * N, (long long)Cb * N, (long long)N * Cb, 1.0f,
            nullptr, nullptr);

        // wy[cs+z][c][n] = sum_d Wzb[c][d] * yT[z][n][d]  (M=1024, N=2304, K=512)
        // -> f32 into d_out, with fused BN sum/sumsq accumulation
        gemm_bt<true, true><<<dim3(N / 128, C / 128, BC), 256, 0, stream>>>(
            Wzb, yT, wyc, Cb, N, 0, (long long)N * Cb, (long long)C * N, 1.0f, psum, pqsm);
    }

    // BN: finalize -> apply (+residual)
    bn_finalize<<<dim3(C / 256), 256, 0, stream>>>(psum, pqsm, mean, istd);
    bn_apply<<<dim3((B * C * N) / (256 * 4)), 256, 0, stream>>>(zo, x, gamma, beta, mean, istd, zo);
}

// Round 3
// 420.685 us; speedup vs baseline: 1.0893x; 1.0364x over previous
//
#include <hip/hip_runtime.h>
#include <hip/hip_bf16.h>
#include <stdint.h>

// non_local_layer: B=8, C=1024, N=48*48=2304, Cb=512. f32 in/out, bf16 MFMA inside.
// R11: R10's symmetric attn (upper-tri blocks + LDS-transpose mirror) helped 120->92us
// but fell short of the 64us live-block arithmetic: counters showed MfmaUtil 31->20,
// VALUBusy 39->11 (machine idler, not slower) -> triangular launch imbalance from
// dispatching 153 dead blocks/z clustered at high bi. Fix: COMPACT the grid to exactly
// 171 blocks/z, decode (bi,bj) from linear index. Also pad mirror tile stride 136->140
// (70 words, coprime 32) to cut the 568K bank conflicts. Everything else unchanged.

typedef __bf16 bf16;
typedef __attribute__((ext_vector_type(8))) __bf16 bf16x8;
typedef __attribute__((ext_vector_type(4))) float f32x4;

// ---------------- GEMM: 128x128 tile, BK=64, 4 waves x (4x4) 16x16x32 MFMA ----------------
// bt-form: D[m][n] = sum_k A[m][k]*B[n][k]; per-z strides sA/sB/sD; D ld=N; alpha scale.
// LDS: 128 rows x 8 chunks of 16B; chunk (row,s) holds global k-chunk s^(row&7).
// BNRED: accumulate sum/sumsq of D over columns (n) per row (channel) into ps/pq.
template <bool F32OUT, bool BNRED>
__global__ __launch_bounds__(256)
void gemm_bt(const bf16* __restrict__ Ag, const bf16* __restrict__ Bg,
             void* __restrict__ Dg, int K, int N,
             long long sA, long long sB, long long sD, float alpha,
             float* __restrict__ ps, float* __restrict__ pq)
{
    __shared__ char lds[32768];            // A tile 16 KB + B tile 16 KB
    char* ldsA = lds;
    char* ldsB = lds + 16384;

    const int lane = threadIdx.x & 63;
    const int wv   = threadIdx.x >> 6;     // 4 waves, 2x2 arrangement
    const int wm   = wv >> 1;
    const int wn   = wv & 1;

    const bf16* Ab = Ag + (long long)blockIdx.z * sA + (long long)blockIdx.y * 128 * K;
    const bf16* Bb = Bg + (long long)blockIdx.z * sB + (long long)blockIdx.x * 128 * K;

    f32x4 acc[4][4];
    #pragma unroll
    for (int i = 0; i < 4; ++i)
        #pragma unroll
        for (int j = 0; j < 4; ++j) {
            f32x4 z = {0.f, 0.f, 0.f, 0.f};
            acc[i][j] = z;
        }

    for (int k0 = 0; k0 < K; k0 += 64) {
        #pragma unroll
        for (int t = 0; t < 4; ++t) {
            int ch  = (wv * 4 + t) * 64 + lane;   // 0..1023
            int row = ch >> 3;
            int cc  = (ch & 7) ^ (row & 7);
            bf16x8 va = *(const bf16x8*)(Ab + (long long)row * K + k0 + cc * 8);
            bf16x8 vb = *(const bf16x8*)(Bb + (long long)row * K + k0 + cc * 8);
            *(bf16x8*)(ldsA + ch * 16) = va;
            *(bf16x8*)(ldsB + ch * 16) = vb;
        }
        __syncthreads();

        #pragma unroll
        for (int kk = 0; kk < 64; kk += 32) {
            bf16x8 af[4], bfr[4];
            #pragma unroll
            for (int i = 0; i < 4; ++i) {
                int r = wm * 64 + i * 16 + (lane & 15);
                int c = ((kk >> 3) + (lane >> 4)) ^ (r & 7);
                af[i] = *(const bf16x8*)(ldsA + r * 128 + c * 16);
            }
            #pragma unroll
            for (int j = 0; j < 4; ++j) {
                int r = wn * 64 + j * 16 + (lane & 15);
                int c = ((kk >> 3) + (lane >> 4)) ^ (r & 7);
                bfr[j] = *(const bf16x8*)(ldsB + r * 128 + c * 16);
            }
            #pragma unroll
            for (int i = 0; i < 4; ++i)
                #pragma unroll
                for (int j = 0; j < 4; ++j)
                    acc[i][j] = __builtin_amdgcn_mfma_f32_16x16x32_bf16(af[i], bfr[j], acc[i][j], 0, 0, 0);
        }
        __syncthreads();
    }

    float* bs = (float*)lds;               // [128] per-channel sum
    float* bq = (float*)(lds + 512);       // [128] per-channel sumsq
    if (BNRED) {
        if (threadIdx.x < 128) { bs[threadIdx.x] = 0.f; bq[threadIdx.x] = 0.f; }
        __syncthreads();
    }

    const int m_base = blockIdx.y * 128 + wm * 64;
    const int n_base = blockIdx.x * 128 + wn * 64;
    float s_it[4][4], q_it[4][4];
    #pragma unroll
    for (int i = 0; i < 4; ++i) {
        #pragma unroll
        for (int t = 0; t < 4; ++t) { s_it[i][t] = 0.f; q_it[i][t] = 0.f; }
    }
    #pragma unroll
    for (int i = 0; i < 4; ++i) {
        #pragma unroll
        for (int j = 0; j < 4; ++j) {
            int col = n_base + j * 16 + (lane & 15);
            #pragma unroll
            for (int t = 0; t < 4; ++t) {
                int rowg = m_base + i * 16 + (lane >> 4) * 4 + t;
                float v = acc[i][j][t] * alpha;
                if (F32OUT) ((float*)Dg)[(long long)blockIdx.z * sD + (long long)rowg * N + col] = v;
                else        ((bf16*)Dg)[(long long)blockIdx.z * sD + (long long)rowg * N + col] = (bf16)v;
                if (BNRED) { s_it[i][t] += v; q_it[i][t] += v * v; }
            }
        }
    }

    if (BNRED) {
        #pragma unroll
        for (int i = 0; i < 4; ++i) {
            #pragma unroll
            for (int t = 0; t < 4; ++t) {
                float s = s_it[i][t], q = q_it[i][t];
                #pragma unroll
                for (int m = 1; m < 16; m <<= 1) {
                    s += __shfl_xor(s, m);
                    q += __shfl_xor(q, m);
                }
                if ((lane & 15) == 0) {
                    int cl = wm * 64 + i * 16 + (lane >> 4) * 4 + t;   // 0..127
                    atomicAdd(&bs[cl], s);
                    atomicAdd(&bq[cl], q);
                }
            }
        }
        __syncthreads();
        if (threadIdx.x < 128) {
            int cg = blockIdx.y * 128 + threadIdx.x;
            atomicAdd(&ps[cg], bs[threadIdx.x]);
            atomicAdd(&pq[cg], bq[threadIdx.x]);
        }
    }
}

// ---------------- symmetric GEMM: D = alpha * X X^T, COMPACT upper-tri launch ----------------
// blockIdx.x in [0,171) decodes to (bi,bj), bj>=bi, 18x18 block grid. Off-diagonal:
// mirror tile to (bj,bi) via LDS transpose (rows padded to 140 bf16 = 70 words, coprime
// with 32 banks). Diagonal: B staging aliases A. Inner loop identical to gemm_bt.
__global__ __launch_bounds__(256)
void gemm_sym(const bf16* __restrict__ Xg, bf16* __restrict__ Dg,
              int K, int N, long long sX, long long sD, float alpha)
{
    // triangular decode: row bi has (18-bi) blocks
    int tlin = blockIdx.x;
    int bi = 0;
    while (tlin >= 18 - bi) { tlin -= 18 - bi; ++bi; }
    const int bj = bi + tlin;
    const bool mir  = (bj > bi);
    const bool diag = (bj == bi);

    __shared__ __align__(16) char lds[35840];   // GEMM: A 16K + B 16K; epilogue: 128 x 140 bf16
    char* ldsA = lds;
    char* ldsB = diag ? lds : (lds + 16384);

    const int lane = threadIdx.x & 63;
    const int wv   = threadIdx.x >> 6;
    const int wm   = wv >> 1;
    const int wn   = wv & 1;

    const bf16* Ab = Xg + (long long)blockIdx.z * sX + (long long)bi * 128 * K;
    const bf16* Bb = Xg + (long long)blockIdx.z * sX + (long long)bj * 128 * K;

    f32x4 acc[4][4];
    #pragma unroll
    for (int i = 0; i < 4; ++i)
        #pragma unroll
        for (int j = 0; j < 4; ++j) {
            f32x4 z = {0.f, 0.f, 0.f, 0.f};
            acc[i][j] = z;
        }

    for (int k0 = 0; k0 < K; k0 += 64) {
        #pragma unroll
        for (int t = 0; t < 4; ++t) {
            int ch  = (wv * 4 + t) * 64 + lane;   // 0..1023
            int row = ch >> 3;
            int cc  = (ch & 7) ^ (row & 7);
            bf16x8 va = *(const bf16x8*)(Ab + (long long)row * K + k0 + cc * 8);
            *(bf16x8*)(ldsA + ch * 16) = va;
            if (!diag) {
                bf16x8 vb = *(const bf16x8*)(Bb + (long long)row * K + k0 + cc * 8);
                *(bf16x8*)(ldsB + ch * 16) = vb;
            }
        }
        __syncthreads();

        #pragma unroll
        for (int kk = 0; kk < 64; kk += 32) {
            bf16x8 af[4], bfr[4];
            #pragma unroll
            for (int i = 0; i < 4; ++i) {
                int r = wm * 64 + i * 16 + (lane & 15);
                int c = ((kk >> 3) + (lane >> 4)) ^ (r & 7);
                af[i] = *(const bf16x8*)(ldsA + r * 128 + c * 16);
            }
            #pragma unroll
            for (int j = 0; j < 4; ++j) {
                int r = wn * 64 + j * 16 + (lane & 15);
                int c = ((kk >> 3) + (lane >> 4)) ^ (r & 7);
                bfr[j] = *(const bf16x8*)(ldsB + r * 128 + c * 16);
            }
            #pragma unroll
            for (int i = 0; i < 4; ++i)
                #pragma unroll
                for (int j = 0; j < 4; ++j)
                    acc[i][j] = __builtin_amdgcn_mfma_f32_16x16x32_bf16(af[i], bfr[j], acc[i][j], 0, 0, 0);
        }
        __syncthreads();
    }

    bf16* Db = Dg + (long long)blockIdx.z * sD;
    bf16 (*tr)[140] = (bf16(*)[140])lds;   // k-loop ended with a barrier; LDS free

    #pragma unroll
    for (int i = 0; i < 4; ++i) {
        #pragma unroll
        for (int j = 0; j < 4; ++j) {
            int c_loc = wn * 64 + j * 16 + (lane & 15);
            int col   = bj * 128 + c_loc;
            #pragma unroll
            for (int t = 0; t < 4; ++t) {
                int r_loc = wm * 64 + i * 16 + (lane >> 4) * 4 + t;
                float v = acc[i][j][t] * alpha;
                Db[(long long)(bi * 128 + r_loc) * N + col] = (bf16)v;
                if (mir) tr[c_loc][r_loc] = (bf16)v;
            }
        }
    }

    if (mir) {
        __syncthreads();
        // 256 threads x 64 bf16: thread (cc=tid>>1, hf=tid&1) copies half a transposed row.
        const int cc = threadIdx.x >> 1, hf = threadIdx.x & 1;
        const bf16* src = &tr[cc][hf * 64];
        bf16* dst = Db + (long long)(bj * 128 + cc) * N + bi * 128 + hf * 64;
        #pragma unroll
        for (int j2 = 0; j2 < 8; ++j2)
            *(bf16x8*)(dst + j2 * 8) = *(const bf16x8*)(src + j2 * 8);
    }
}

// ---------------- f32 -> bf16 bulk convert (weights) ----------------
__global__ __launch_bounds__(256)
void f32_to_bf16(const float* __restrict__ in, bf16* __restrict__ out, int n)
{
    int idx = (blockIdx.x * 256 + threadIdx.x) * 4;
    if (idx < n) {
        float4 v = *(const float4*)(in + idx);
        out[idx + 0] = (bf16)v.x;
        out[idx + 1] = (bf16)v.y;
        out[idx + 2] = (bf16)v.z;
        out[idx + 3] = (bf16)v.w;
    }
}

// ---------------- zero-init BN accumulators (ws is poisoned 0xAA every launch) ----------------
__global__ __launch_bounds__(256)
void zero_f32(float* __restrict__ p)
{
    p[blockIdx.x * 256 + threadIdx.x] = 0.f;
}

// ---------------- batched transpose x[z][C][N] (f32) -> xT[z][N][C] (bf16) ----------------
__global__ __launch_bounds__(256)
void transpose_f32_bf16(const float* __restrict__ x, bf16* __restrict__ xT)
{
    __shared__ bf16 tile[32][33];
    const float* xb = x + (long long)blockIdx.z * 1024 * 2304;
    bf16* xo = xT + (long long)blockIdx.z * 2304 * 1024;
    const int n0 = blockIdx.x * 32;
    const int c0 = blockIdx.y * 32;
    const int tx = threadIdx.x, ty = threadIdx.y;   // (32, 8)
    #pragma unroll
    for (int i = 0; i < 32; i += 8)
        tile[ty + i][tx] = (bf16)xb[(long long)(c0 + ty + i) * 2304 + n0 + tx];
    __syncthreads();
    #pragma unroll
    for (int i = 0; i < 32; i += 8)
        xo[(long long)(n0 + ty + i) * 1024 + c0 + tx] = tile[tx][ty + i];
}

// ---------------- register-resident row softmax (N=2304), one block per row ----------------
__global__ __launch_bounds__(256)
void softmax_rows(bf16* __restrict__ S)
{
    bf16* p = S + (long long)blockIdx.x * 2304;
    const int t = threadIdx.x;
    __shared__ float red[256];

    bf16x8 v8 = *(const bf16x8*)(p + t * 8);
    float vt = (float)p[2048 + t];
    float f[8];
    float mx = vt;
    #pragma unroll
    for (int i = 0; i < 8; ++i) { f[i] = (float)v8[i]; mx = fmaxf(mx, f[i]); }

    red[t] = mx; __syncthreads();
    for (int s = 128; s > 0; s >>= 1) { if (t < s) red[t] = fmaxf(red[t], red[t + s]); __syncthreads(); }
    mx = red[0];
    __syncthreads();

    float sum = 0.f;
    #pragma unroll
    for (int i = 0; i < 8; ++i) { f[i] = __expf(f[i] - mx); sum += f[i]; }
    vt = __expf(vt - mx); sum += vt;

    red[t] = sum; __syncthreads();
    for (int s = 128; s > 0; s >>= 1) { if (t < s) red[t] += red[t + s]; __syncthreads(); }
    float inv = 1.0f / red[0];

    bf16x8 o;
    #pragma unroll
    for (int i = 0; i < 8; ++i) o[i] = (bf16)(f[i] * inv);
    *(bf16x8*)(p + t * 8) = o;
    p[2048 + t] = (bf16)(vt * inv);
}

// ---------------- BN finalize: psum/pqsm already summed over all batches ----------------
__global__ __launch_bounds__(256)
void bn_finalize(const float* __restrict__ ps, const float* __restrict__ pq,
                 float* __restrict__ mean, float* __restrict__ istd)
{
    int c = blockIdx.x * 256 + threadIdx.x;   // grid 4 x 256 = 1024
    float mu = ps[c] / 18432.0f;
    mean[c] = mu;
    istd[c] = rsqrtf(pq[c] / 18432.0f - mu * mu + 1e-5f);
}

// ---------------- BN apply + residual, all f32, in place on wy(=d_out) ----------------
__global__ __launch_bounds__(256)
void bn_apply(const float* __restrict__ wy, const float* __restrict__ x,
              const float* __restrict__ gamma, const float* __restrict__ beta,
              const float* __restrict__ mean, const float* __restrict__ istd,
              float* __restrict__ z)
{
    long long idx = ((long long)blockIdx.x * 256 + threadIdx.x) * 4;
    int c = (int)((idx / 2304) & 1023);    // layout [B][C][N], N divisible by 4
    float sc = gamma[c] * istd[c];
    float sh = beta[c] - mean[c] * sc;
    float4 w  = *(const float4*)(wy + idx);
    float4 xv = *(const float4*)(x + idx);
    float4 o;
    o.x = w.x * sc + sh + xv.x;
    o.y = w.y * sc + sh + xv.y;
    o.z = w.z * sc + sh + xv.z;
    o.w = w.w * sc + sh + xv.w;
    *(float4*)(z + idx) = o;
}

extern "C" void kernel_launch(void* const* d_in, const int* in_sizes, int n_in,
                              void* d_out, int out_size, void* d_ws, size_t ws_size,
                              hipStream_t stream)
{
    const float* x     = (const float*)d_in[0];
    const float* Wg    = (const float*)d_in[1];
    const float* Wz    = (const float*)d_in[2];
    const float* gamma = (const float*)d_in[3];
    const float* beta  = (const float*)d_in[4];
    float* zo = (float*)d_out;             // f32 output; also serves as the wy buffer

    const int B = 8, C = 1024, Cb = 512, N = 2304;

    // ws-adaptive batch chunking: BC in {8,4,2,1}, largest whose footprint fits.
    const size_t fixedB = ((size_t)Cb * C * 2) * 2 + (size_t)C * 4 * 4 + 4096;
    const size_t perB   = ((size_t)N * C + (size_t)Cb * N + (size_t)N * N + (size_t)N * Cb) * 2 + 1024;
    int BC = 8;
    while (BC > 1 && fixedB + perB * (size_t)BC > ws_size) BC >>= 1;

    char* p = (char*)d_ws;
    auto alloc = [&](size_t bytes) { char* r = p; p += (bytes + 255) & ~(size_t)255; return r; };
    bf16*  Wgb  = (bf16*)alloc((size_t)Cb * C * 2);
    bf16*  Wzb  = (bf16*)alloc((size_t)C * Cb * 2);
    float* psum = (float*)alloc((size_t)C * 4);   // contiguous with pqsm (both 4 KB)
    float* pqsm = (float*)alloc((size_t)C * 4);
    float* mean = (float*)alloc((size_t)C * 4);
    float* istd = (float*)alloc((size_t)C * 4);
    bf16*  xT   = (bf16*)alloc((size_t)BC * N * C * 2);
    bf16*  g    = (bf16*)alloc((size_t)BC * Cb * N * 2);
    bf16*  attn = (bf16*)alloc((size_t)BC * N * N * 2);
    bf16*  yT   = (bf16*)alloc((size_t)BC * N * Cb * 2);

    // 0) weights f32 -> bf16; zero BN accumulators (psum+pqsm contiguous, 2048 floats)
    f32_to_bf16<<<dim3((Cb * C) / (256 * 4)), 256, 0, stream>>>(Wg, Wgb, Cb * C);
    f32_to_bf16<<<dim3((C * Cb) / (256 * 4)), 256, 0, stream>>>(Wz, Wzb, C * Cb);
    zero_f32<<<dim3(8), 256, 0, stream>>>(psum);

    for (int cs = 0; cs < B; cs += BC) {
        const float* xc = x + (long long)cs * C * N;
        float* wyc = zo + (long long)cs * C * N;

        // xT[z][n][c] = x[cs+z][c][n] (bf16)
        transpose_f32_bf16<<<dim3(N / 32, C / 32, BC), dim3(32, 8), 0, stream>>>(xc, xT);

        // g[z][d][n] = sum_c Wgb[d][c] * xT[z][n][c]   (M=512, N=2304, K=1024)
        gemm_bt<false, false><<<dim3(N / 128, Cb / 128, BC), 256, 0, stream>>>(
            Wgb, xT, g, C, N, 0, (long long)N * C, (long long)Cb * N, 1.0f, nullptr, nullptr);

        // attn[z][n][m] = sum_c xT[z][n][c]*xT[z][m][c] / 2304  (M=N=2304, K=1024)
        // symmetric: compact triangular launch (171 live blocks/z), mirror via LDS
        gemm_sym<<<dim3(171, 1, BC), 256, 0, stream>>>(
            xT, attn, C, N, (long long)N * C, (long long)N * N, 1.0f / 2304.0f);

        // row softmax, one read one write
        softmax_rows<<<dim3(BC * N), 256, 0, stream>>>(attn);

        // yT[z][n][d] = sum_m attn[z][n][m] * g[z][d][m]  (M=2304, N=512, K=2304)
        gemm_bt<false, false><<<dim3(Cb / 128, N / 128, BC), 256, 0, stream>>>(
            attn, g, yT, N, Cb, (long long)N * N, (long long)Cb * N, (long long)N * Cb, 1.0f,
            nullptr, nullptr);

        // wy[cs+z][c][n] = sum_d Wzb[c][d] * yT[z][n][d]  (M=1024, N=2304, K=512)
        // -> f32 into d_out, with fused BN sum/sumsq accumulation
        gemm_bt<true, true><<<dim3(N / 128, C / 128, BC), 256, 0, stream>>>(
            Wzb, yT, wyc, Cb, N, 0, (long long)N * Cb, (long long)C * N, 1.0f, psum, pqsm);
    }

    // BN: finalize -> apply (+residual)
    bn_finalize<<<dim3(C / 256), 256, 0, stream>>>(psum, pqsm, mean, istd);
    bn_apply<<<dim3((B * C * N) / (256 * 4)), 256, 0, stream>>>(zo, x, gamma, beta, mean, istd, zo);
}

// Round 4
// 418.062 us; speedup vs baseline: 1.0962x; 1.0063x over previous
//
#include <hip/hip_runtime.h>
#include <hip/hip_bf16.h>
#include <stdint.h>

// non_local_layer: B=8, C=1024, N=48*48=2304, Cb=512. f32 in/out, bf16 MFMA inside.
// R12: R11 post-mortem: compact launch was neutral -> imbalance theory wrong. Real
// signal: per-block FETCH 72.6 KB (gemm_bt attn) vs 111.5 KB (gemm_sym) = +54%; the
// K-loop drains vmcnt(0) per barrier so staging-hit latency sets block service time
// (MfmaUtil 31->20, VALUBusy 39->11). Cause: ~540 resident blocks span ~3 z's; each
// XCD L2 (4MB) thrashes over 3 x 4.7MB xT slices. Fix: z-major XCD affinity --
// d = bz*171+bx; zz = d % gridDim.z; t = d / gridDim.z. With BC=8, same-zz blocks all
// land on one XCD (dispatch round-robin), so each XCD caches exactly its own xT[z].
// Bank-conflict fingerprint 567936 is understood-minor (~0.5us), left alone.

typedef __bf16 bf16;
typedef __attribute__((ext_vector_type(8))) __bf16 bf16x8;
typedef __attribute__((ext_vector_type(4))) float f32x4;

// ---------------- GEMM: 128x128 tile, BK=64, 4 waves x (4x4) 16x16x32 MFMA ----------------
// bt-form: D[m][n] = sum_k A[m][k]*B[n][k]; per-z strides sA/sB/sD; D ld=N; alpha scale.
// LDS: 128 rows x 8 chunks of 16B; chunk (row,s) holds global k-chunk s^(row&7).
// BNRED: accumulate sum/sumsq of D over columns (n) per row (channel) into ps/pq.
template <bool F32OUT, bool BNRED>
__global__ __launch_bounds__(256)
void gemm_bt(const bf16* __restrict__ Ag, const bf16* __restrict__ Bg,
             void* __restrict__ Dg, int K, int N,
             long long sA, long long sB, long long sD, float alpha,
             float* __restrict__ ps, float* __restrict__ pq)
{
    __shared__ char lds[32768];            // A tile 16 KB + B tile 16 KB
    char* ldsA = lds;
    char* ldsB = lds + 16384;

    const int lane = threadIdx.x & 63;
    const int wv   = threadIdx.x >> 6;     // 4 waves, 2x2 arrangement
    const int wm   = wv >> 1;
    const int wn   = wv & 1;

    const bf16* Ab = Ag + (long long)blockIdx.z * sA + (long long)blockIdx.y * 128 * K;
    const bf16* Bb = Bg + (long long)blockIdx.z * sB + (long long)blockIdx.x * 128 * K;

    f32x4 acc[4][4];
    #pragma unroll
    for (int i = 0; i < 4; ++i)
        #pragma unroll
        for (int j = 0; j < 4; ++j) {
            f32x4 z = {0.f, 0.f, 0.f, 0.f};
            acc[i][j] = z;
        }

    for (int k0 = 0; k0 < K; k0 += 64) {
        #pragma unroll
        for (int t = 0; t < 4; ++t) {
            int ch  = (wv * 4 + t) * 64 + lane;   // 0..1023
            int row = ch >> 3;
            int cc  = (ch & 7) ^ (row & 7);
            bf16x8 va = *(const bf16x8*)(Ab + (long long)row * K + k0 + cc * 8);
            bf16x8 vb = *(const bf16x8*)(Bb + (long long)row * K + k0 + cc * 8);
            *(bf16x8*)(ldsA + ch * 16) = va;
            *(bf16x8*)(ldsB + ch * 16) = vb;
        }
        __syncthreads();

        #pragma unroll
        for (int kk = 0; kk < 64; kk += 32) {
            bf16x8 af[4], bfr[4];
            #pragma unroll
            for (int i = 0; i < 4; ++i) {
                int r = wm * 64 + i * 16 + (lane & 15);
                int c = ((kk >> 3) + (lane >> 4)) ^ (r & 7);
                af[i] = *(const bf16x8*)(ldsA + r * 128 + c * 16);
            }
            #pragma unroll
            for (int j = 0; j < 4; ++j) {
                int r = wn * 64 + j * 16 + (lane & 15);
                int c = ((kk >> 3) + (lane >> 4)) ^ (r & 7);
                bfr[j] = *(const bf16x8*)(ldsB + r * 128 + c * 16);
            }
            #pragma unroll
            for (int i = 0; i < 4; ++i)
                #pragma unroll
                for (int j = 0; j < 4; ++j)
                    acc[i][j] = __builtin_amdgcn_mfma_f32_16x16x32_bf16(af[i], bfr[j], acc[i][j], 0, 0, 0);
        }
        __syncthreads();
    }

    float* bs = (float*)lds;               // [128] per-channel sum
    float* bq = (float*)(lds + 512);       // [128] per-channel sumsq
    if (BNRED) {
        if (threadIdx.x < 128) { bs[threadIdx.x] = 0.f; bq[threadIdx.x] = 0.f; }
        __syncthreads();
    }

    const int m_base = blockIdx.y * 128 + wm * 64;
    const int n_base = blockIdx.x * 128 + wn * 64;
    float s_it[4][4], q_it[4][4];
    #pragma unroll
    for (int i = 0; i < 4; ++i) {
        #pragma unroll
        for (int t = 0; t < 4; ++t) { s_it[i][t] = 0.f; q_it[i][t] = 0.f; }
    }
    #pragma unroll
    for (int i = 0; i < 4; ++i) {
        #pragma unroll
        for (int j = 0; j < 4; ++j) {
            int col = n_base + j * 16 + (lane & 15);
            #pragma unroll
            for (int t = 0; t < 4; ++t) {
                int rowg = m_base + i * 16 + (lane >> 4) * 4 + t;
                float v = acc[i][j][t] * alpha;
                if (F32OUT) ((float*)Dg)[(long long)blockIdx.z * sD + (long long)rowg * N + col] = v;
                else        ((bf16*)Dg)[(long long)blockIdx.z * sD + (long long)rowg * N + col] = (bf16)v;
                if (BNRED) { s_it[i][t] += v; q_it[i][t] += v * v; }
            }
        }
    }

    if (BNRED) {
        #pragma unroll
        for (int i = 0; i < 4; ++i) {
            #pragma unroll
            for (int t = 0; t < 4; ++t) {
                float s = s_it[i][t], q = q_it[i][t];
                #pragma unroll
                for (int m = 1; m < 16; m <<= 1) {
                    s += __shfl_xor(s, m);
                    q += __shfl_xor(q, m);
                }
                if ((lane & 15) == 0) {
                    int cl = wm * 64 + i * 16 + (lane >> 4) * 4 + t;   // 0..127
                    atomicAdd(&bs[cl], s);
                    atomicAdd(&bq[cl], q);
                }
            }
        }
        __syncthreads();
        if (threadIdx.x < 128) {
            int cg = blockIdx.y * 128 + threadIdx.x;
            atomicAdd(&ps[cg], bs[threadIdx.x]);
            atomicAdd(&pq[cg], bq[threadIdx.x]);
        }
    }
}

// ---------------- symmetric GEMM: D = alpha * X X^T, compact upper-tri, z-major XCD ----------------
// Linear dispatch id d = blockIdx.z*171 + blockIdx.x; zz = d % gridDim.z (XCD affinity
// when gridDim.z==8: round-robin puts all same-zz blocks on one XCD, whose L2 then
// holds only xT[zz]); t = d / gridDim.z in [0,171) decodes to (bi,bj), bj>=bi.
// Off-diagonal: mirror tile to (bj,bi) via LDS transpose (140-stride rows). Diagonal:
// B staging aliases A. Inner loop identical to gemm_bt.
__global__ __launch_bounds__(256)
void gemm_sym(const bf16* __restrict__ Xg, bf16* __restrict__ Dg,
              int K, int N, long long sX, long long sD, float alpha)
{
    const int NZ = gridDim.z;
    const int d  = blockIdx.z * 171 + blockIdx.x;
    const int zz = d % NZ;
    int tlin     = d / NZ;                 // 0..170, bijective (171*NZ blocks total)
    int bi = 0;
    while (tlin >= 18 - bi) { tlin -= 18 - bi; ++bi; }
    const int bj = bi + tlin;
    const bool mir  = (bj > bi);
    const bool diag = (bj == bi);

    __shared__ __align__(16) char lds[35840];   // GEMM: A 16K + B 16K; epilogue: 128 x 140 bf16
    char* ldsA = lds;
    char* ldsB = diag ? lds : (lds + 16384);

    const int lane = threadIdx.x & 63;
    const int wv   = threadIdx.x >> 6;
    const int wm   = wv >> 1;
    const int wn   = wv & 1;

    const bf16* Ab = Xg + (long long)zz * sX + (long long)bi * 128 * K;
    const bf16* Bb = Xg + (long long)zz * sX + (long long)bj * 128 * K;

    f32x4 acc[4][4];
    #pragma unroll
    for (int i = 0; i < 4; ++i)
        #pragma unroll
        for (int j = 0; j < 4; ++j) {
            f32x4 z = {0.f, 0.f, 0.f, 0.f};
            acc[i][j] = z;
        }

    for (int k0 = 0; k0 < K; k0 += 64) {
        #pragma unroll
        for (int t = 0; t < 4; ++t) {
            int ch  = (wv * 4 + t) * 64 + lane;   // 0..1023
            int row = ch >> 3;
            int cc  = (ch & 7) ^ (row & 7);
            bf16x8 va = *(const bf16x8*)(Ab + (long long)row * K + k0 + cc * 8);
            *(bf16x8*)(ldsA + ch * 16) = va;
            if (!diag) {
                bf16x8 vb = *(const bf16x8*)(Bb + (long long)row * K + k0 + cc * 8);
                *(bf16x8*)(ldsB + ch * 16) = vb;
            }
        }
        __syncthreads();

        #pragma unroll
        for (int kk = 0; kk < 64; kk += 32) {
            bf16x8 af[4], bfr[4];
            #pragma unroll
            for (int i = 0; i < 4; ++i) {
                int r = wm * 64 + i * 16 + (lane & 15);
                int c = ((kk >> 3) + (lane >> 4)) ^ (r & 7);
                af[i] = *(const bf16x8*)(ldsA + r * 128 + c * 16);
            }
            #pragma unroll
            for (int j = 0; j < 4; ++j) {
                int r = wn * 64 + j * 16 + (lane & 15);
                int c = ((kk >> 3) + (lane >> 4)) ^ (r & 7);
                bfr[j] = *(const bf16x8*)(ldsB + r * 128 + c * 16);
            }
            #pragma unroll
            for (int i = 0; i < 4; ++i)
                #pragma unroll
                for (int j = 0; j < 4; ++j)
                    acc[i][j] = __builtin_amdgcn_mfma_f32_16x16x32_bf16(af[i], bfr[j], acc[i][j], 0, 0, 0);
        }
        __syncthreads();
    }

    bf16* Db = Dg + (long long)zz * sD;
    bf16 (*tr)[140] = (bf16(*)[140])lds;   // k-loop ended with a barrier; LDS free

    #pragma unroll
    for (int i = 0; i < 4; ++i) {
        #pragma unroll
        for (int j = 0; j < 4; ++j) {
            int c_loc = wn * 64 + j * 16 + (lane & 15);
            int col   = bj * 128 + c_loc;
            #pragma unroll
            for (int t = 0; t < 4; ++t) {
                int r_loc = wm * 64 + i * 16 + (lane >> 4) * 4 + t;
                float v = acc[i][j][t] * alpha;
                Db[(long long)(bi * 128 + r_loc) * N + col] = (bf16)v;
                if (mir) tr[c_loc][r_loc] = (bf16)v;
            }
        }
    }

    if (mir) {
        __syncthreads();
        // 256 threads x 64 bf16: thread (cc=tid>>1, hf=tid&1) copies half a transposed row.
        const int cc = threadIdx.x >> 1, hf = threadIdx.x & 1;
        const bf16* src = &tr[cc][hf * 64];
        bf16* dst = Db + (long long)(bj * 128 + cc) * N + bi * 128 + hf * 64;
        #pragma unroll
        for (int j2 = 0; j2 < 8; ++j2)
            *(bf16x8*)(dst + j2 * 8) = *(const bf16x8*)(src + j2 * 8);
    }
}

// ---------------- f32 -> bf16 bulk convert (weights) ----------------
__global__ __launch_bounds__(256)
void f32_to_bf16(const float* __restrict__ in, bf16* __restrict__ out, int n)
{
    int idx = (blockIdx.x * 256 + threadIdx.x) * 4;
    if (idx < n) {
        float4 v = *(const float4*)(in + idx);
        out[idx + 0] = (bf16)v.x;
        out[idx + 1] = (bf16)v.y;
        out[idx + 2] = (bf16)v.z;
        out[idx + 3] = (bf16)v.w;
    }
}

// ---------------- zero-init BN accumulators (ws is poisoned 0xAA every launch) ----------------
__global__ __launch_bounds__(256)
void zero_f32(float* __restrict__ p)
{
    p[blockIdx.x * 256 + threadIdx.x] = 0.f;
}

// ---------------- batched transpose x[z][C][N] (f32) -> xT[z][N][C] (bf16) ----------------
__global__ __launch_bounds__(256)
void transpose_f32_bf16(const float* __restrict__ x, bf16* __restrict__ xT)
{
    __shared__ bf16 tile[32][33];
    const float* xb = x + (long long)blockIdx.z * 1024 * 2304;
    bf16* xo = xT + (long long)blockIdx.z * 2304 * 1024;
    const int n0 = blockIdx.x * 32;
    const int c0 = blockIdx.y * 32;
    const int tx = threadIdx.x, ty = threadIdx.y;   // (32, 8)
    #pragma unroll
    for (int i = 0; i < 32; i += 8)
        tile[ty + i][tx] = (bf16)xb[(long long)(c0 + ty + i) * 2304 + n0 + tx];
    __syncthreads();
    #pragma unroll
    for (int i = 0; i < 32; i += 8)
        xo[(long long)(n0 + ty + i) * 1024 + c0 + tx] = tile[tx][ty + i];
}

// ---------------- register-resident row softmax (N=2304), one block per row ----------------
__global__ __launch_bounds__(256)
void softmax_rows(bf16* __restrict__ S)
{
    bf16* p = S + (long long)blockIdx.x * 2304;
    const int t = threadIdx.x;
    __shared__ float red[256];

    bf16x8 v8 = *(const bf16x8*)(p + t * 8);
    float vt = (float)p[2048 + t];
    float f[8];
    float mx = vt;
    #pragma unroll
    for (int i = 0; i < 8; ++i) { f[i] = (float)v8[i]; mx = fmaxf(mx, f[i]); }

    red[t] = mx; __syncthreads();
    for (int s = 128; s > 0; s >>= 1) { if (t < s) red[t] = fmaxf(red[t], red[t + s]); __syncthreads(); }
    mx = red[0];
    __syncthreads();

    float sum = 0.f;
    #pragma unroll
    for (int i = 0; i < 8; ++i) { f[i] = __expf(f[i] - mx); sum += f[i]; }
    vt = __expf(vt - mx); sum += vt;

    red[t] = sum; __syncthreads();
    for (int s = 128; s > 0; s >>= 1) { if (t < s) red[t] += red[t + s]; __syncthreads(); }
    float inv = 1.0f / red[0];

    bf16x8 o;
    #pragma unroll
    for (int i = 0; i < 8; ++i) o[i] = (bf16)(f[i] * inv);
    *(bf16x8*)(p + t * 8) = o;
    p[2048 + t] = (bf16)(vt * inv);
}

// ---------------- BN finalize: psum/pqsm already summed over all batches ----------------
__global__ __launch_bounds__(256)
void bn_finalize(const float* __restrict__ ps, const float* __restrict__ pq,
                 float* __restrict__ mean, float* __restrict__ istd)
{
    int c = blockIdx.x * 256 + threadIdx.x;   // grid 4 x 256 = 1024
    float mu = ps[c] / 18432.0f;
    mean[c] = mu;
    istd[c] = rsqrtf(pq[c] / 18432.0f - mu * mu + 1e-5f);
}

// ---------------- BN apply + residual, all f32, in place on wy(=d_out) ----------------
__global__ __launch_bounds__(256)
void bn_apply(const float* __restrict__ wy, const float* __restrict__ x,
              const float* __restrict__ gamma, const float* __restrict__ beta,
              const float* __restrict__ mean, const float* __restrict__ istd,
              float* __restrict__ z)
{
    long long idx = ((long long)blockIdx.x * 256 + threadIdx.x) * 4;
    int c = (int)((idx / 2304) & 1023);    // layout [B][C][N], N divisible by 4
    float sc = gamma[c] * istd[c];
    float sh = beta[c] - mean[c] * sc;
    float4 w  = *(const float4*)(wy + idx);
    float4 xv = *(const float4*)(x + idx);
    float4 o;
    o.x = w.x * sc + sh + xv.x;
    o.y = w.y * sc + sh + xv.y;
    o.z = w.z * sc + sh + xv.z;
    o.w = w.w * sc + sh + xv.w;
    *(float4*)(z + idx) = o;
}

extern "C" void kernel_launch(void* const* d_in, const int* in_sizes, int n_in,
                              void* d_out, int out_size, void* d_ws, size_t ws_size,
                              hipStream_t stream)
{
    const float* x     = (const float*)d_in[0];
    const float* Wg    = (const float*)d_in[1];
    const float* Wz    = (const float*)d_in[2];
    const float* gamma = (const float*)d_in[3];
    const float* beta  = (const float*)d_in[4];
    float* zo = (float*)d_out;             // f32 output; also serves as the wy buffer

    const int B = 8, C = 1024, Cb = 512, N = 2304;

    // ws-adaptive batch chunking: BC in {8,4,2,1}, largest whose footprint fits.
    const size_t fixedB = ((size_t)Cb * C * 2) * 2 + (size_t)C * 4 * 4 + 4096;
    const size_t perB   = ((size_t)N * C + (size_t)Cb * N + (size_t)N * N + (size_t)N * Cb) * 2 + 1024;
    int BC = 8;
    while (BC > 1 && fixedB + perB * (size_t)BC > ws_size) BC >>= 1;

    char* p = (char*)d_ws;
    auto alloc = [&](size_t bytes) { char* r = p; p += (bytes + 255) & ~(size_t)255; return r; };
    bf16*  Wgb  = (bf16*)alloc((size_t)Cb * C * 2);
    bf16*  Wzb  = (bf16*)alloc((size_t)C * Cb * 2);
    float* psum = (float*)alloc((size_t)C * 4);   // contiguous with pqsm (both 4 KB)
    float* pqsm = (float*)alloc((size_t)C * 4);
    float* mean = (float*)alloc((size_t)C * 4);
    float* istd = (float*)alloc((size_t)C * 4);
    bf16*  xT   = (bf16*)alloc((size_t)BC * N * C * 2);
    bf16*  g    = (bf16*)alloc((size_t)BC * Cb * N * 2);
    bf16*  attn = (bf16*)alloc((size_t)BC * N * N * 2);
    bf16*  yT   = (bf16*)alloc((size_t)BC * N * Cb * 2);

    // 0) weights f32 -> bf16; zero BN accumulators (psum+pqsm contiguous, 2048 floats)
    f32_to_bf16<<<dim3((Cb * C) / (256 * 4)), 256, 0, stream>>>(Wg, Wgb, Cb * C);
    f32_to_bf16<<<dim3((C * Cb) / (256 * 4)), 256, 0, stream>>>(Wz, Wzb, C * Cb);
    zero_f32<<<dim3(8), 256, 0, stream>>>(psum);

    for (int cs = 0; cs < B; cs += BC) {
        const float* xc = x + (long long)cs * C * N;
        float* wyc = zo + (long long)cs * C * N;

        // xT[z][n][c] = x[cs+z][c][n] (bf16)
        transpose_f32_bf16<<<dim3(N / 32, C / 32, BC), dim3(32, 8), 0, stream>>>(xc, xT);

        // g[z][d][n] = sum_c Wgb[d][c] * xT[z][n][c]   (M=512, N=2304, K=1024)
        gemm_bt<false, false><<<dim3(N / 128, Cb / 128, BC), 256, 0, stream>>>(
            Wgb, xT, g, C, N, 0, (long long)N * C, (long long)Cb * N, 1.0f, nullptr, nullptr);

        // attn[z][n][m] = sum_c xT[z][n][c]*xT[z][m][c] / 2304  (M=N=2304, K=1024)
        // symmetric: compact triangular launch (171 live blocks/z), z-major XCD affinity
        gemm_sym<<<dim3(171, 1, BC), 256, 0, stream>>>(
            xT, attn, C, N, (long long)N * C, (long long)N * N, 1.0f / 2304.0f);

        // row softmax, one read one write
        softmax_rows<<<dim3(BC * N), 256, 0, stream>>>(attn);

        // yT[z][n][d] = sum_m attn[z][n][m] * g[z][d][m]  (M=2304, N=512, K=2304)
        gemm_bt<false, false><<<dim3(Cb / 128, N / 128, BC), 256, 0, stream>>>(
            attn, g, yT, N, Cb, (long long)N * N, (long long)Cb * N, (long long)N * Cb, 1.0f,
            nullptr, nullptr);

        // wy[cs+z][c][n] = sum_d Wzb[c][d] * yT[z][n][d]  (M=1024, N=2304, K=512)
        // -> f32 into d_out, with fused BN sum/sumsq accumulation
        gemm_bt<true, true><<<dim3(N / 128, C / 128, BC), 256, 0, stream>>>(
            Wzb, yT, wyc, Cb, N, 0, (long long)N * Cb, (long long)C * N, 1.0f, psum, pqsm);
    }

    // BN: finalize -> apply (+residual)
    bn_finalize<<<dim3(C / 256), 256, 0, stream>>>(psum, pqsm, mean, istd);
    bn_apply<<<dim3((B * C * N) / (256 * 4)), 256, 0, stream>>>(zo, x, gamma, beta, mean, istd, zo);
}

// Round 5
// 404.891 us; speedup vs baseline: 1.1318x; 1.0325x over previous
//
#include <hip/hip_runtime.h>
#include <hip/hip_bf16.h>
#include <stdint.h>

// non_local_layer: B=8, C=1024, N=48*48=2304, Cb=512. f32 in/out, bf16 MFMA inside.
// R13: R12 proved z-major XCD affinity collapses FETCH 5x (152->31 MB on gemm_sym).
// Apply the same remap to g/y/wy GEMMs (1-D grid, zz = d % nz; inner-dim order chosen
// so same-XCD-consecutive blocks share a tile: y -> bx inner (share attn row-tile,
// g[z] 2.36MB L2-resident); g/wy -> by inner (share B tile, xT/yT resident)).
// Also: (a) gemm_sym mirror epilogue ds_write_b16 x64 -> ds_write_b64 x16;
// (b) wy stored bf16 (BN stats stay f32 via fused accumulators) -> halves wy write
// and bn_apply read traffic. gemm_sym keeps R12 mapping (FETCH fingerprint ~31 MB).

typedef __bf16 bf16;
typedef __attribute__((ext_vector_type(8))) __bf16 bf16x8;
typedef __attribute__((ext_vector_type(4))) __bf16 bf16x4;
typedef __attribute__((ext_vector_type(4))) float f32x4;

// ---------------- GEMM: 128x128 tile, BK=64, 4 waves x (4x4) 16x16x32 MFMA ----------------
// bt-form: D[m][n] = sum_k A[m][k]*B[n][k]; per-z strides sA/sB/sD; D ld=N; alpha scale.
// 1-D grid with z-major XCD affinity: d = blockIdx.x; zz = d % nz (dispatch round-robin
// puts all same-zz blocks on one XCD); t = d / nz; inner/outer split per template BXI.
// LDS: 128 rows x 8 chunks of 16B; chunk (row,s) holds global k-chunk s^(row&7).
// BNRED: accumulate sum/sumsq of D over columns (n) per row (channel) into ps/pq.
template <bool F32OUT, bool BNRED, bool BXI>
__global__ __launch_bounds__(256)
void gemm_btz(const bf16* __restrict__ Ag, const bf16* __restrict__ Bg,
              void* __restrict__ Dg, int K, int N,
              long long sA, long long sB, long long sD, float alpha,
              float* __restrict__ ps, float* __restrict__ pq, int nInner, int nz)
{
    const int d  = blockIdx.x;
    const int zz = d % nz;
    const int t0 = d / nz;
    const int bI = t0 % nInner;
    const int bO = t0 / nInner;
    const int bx = BXI ? bI : bO;
    const int by = BXI ? bO : bI;

    __shared__ char lds[32768];            // A tile 16 KB + B tile 16 KB
    char* ldsA = lds;
    char* ldsB = lds + 16384;

    const int lane = threadIdx.x & 63;
    const int wv   = threadIdx.x >> 6;     // 4 waves, 2x2 arrangement
    const int wm   = wv >> 1;
    const int wn   = wv & 1;

    const bf16* Ab = Ag + (long long)zz * sA + (long long)by * 128 * K;
    const bf16* Bb = Bg + (long long)zz * sB + (long long)bx * 128 * K;

    f32x4 acc[4][4];
    #pragma unroll
    for (int i = 0; i < 4; ++i)
        #pragma unroll
        for (int j = 0; j < 4; ++j) {
            f32x4 z = {0.f, 0.f, 0.f, 0.f};
            acc[i][j] = z;
        }

    for (int k0 = 0; k0 < K; k0 += 64) {
        #pragma unroll
        for (int t = 0; t < 4; ++t) {
            int ch  = (wv * 4 + t) * 64 + lane;   // 0..1023
            int row = ch >> 3;
            int cc  = (ch & 7) ^ (row & 7);
            bf16x8 va = *(const bf16x8*)(Ab + (long long)row * K + k0 + cc * 8);
            bf16x8 vb = *(const bf16x8*)(Bb + (long long)row * K + k0 + cc * 8);
            *(bf16x8*)(ldsA + ch * 16) = va;
            *(bf16x8*)(ldsB + ch * 16) = vb;
        }
        __syncthreads();

        #pragma unroll
        for (int kk = 0; kk < 64; kk += 32) {
            bf16x8 af[4], bfr[4];
            #pragma unroll
            for (int i = 0; i < 4; ++i) {
                int r = wm * 64 + i * 16 + (lane & 15);
                int c = ((kk >> 3) + (lane >> 4)) ^ (r & 7);
                af[i] = *(const bf16x8*)(ldsA + r * 128 + c * 16);
            }
            #pragma unroll
            for (int j = 0; j < 4; ++j) {
                int r = wn * 64 + j * 16 + (lane & 15);
                int c = ((kk >> 3) + (lane >> 4)) ^ (r & 7);
                bfr[j] = *(const bf16x8*)(ldsB + r * 128 + c * 16);
            }
            #pragma unroll
            for (int i = 0; i < 4; ++i)
                #pragma unroll
                for (int j = 0; j < 4; ++j)
                    acc[i][j] = __builtin_amdgcn_mfma_f32_16x16x32_bf16(af[i], bfr[j], acc[i][j], 0, 0, 0);
        }
        __syncthreads();
    }

    float* bs = (float*)lds;               // [128] per-channel sum
    float* bq = (float*)(lds + 512);       // [128] per-channel sumsq
    if (BNRED) {
        if (threadIdx.x < 128) { bs[threadIdx.x] = 0.f; bq[threadIdx.x] = 0.f; }
        __syncthreads();
    }

    const int m_base = by * 128 + wm * 64;
    const int n_base = bx * 128 + wn * 64;
    float s_it[4][4], q_it[4][4];
    #pragma unroll
    for (int i = 0; i < 4; ++i) {
        #pragma unroll
        for (int t = 0; t < 4; ++t) { s_it[i][t] = 0.f; q_it[i][t] = 0.f; }
    }
    #pragma unroll
    for (int i = 0; i < 4; ++i) {
        #pragma unroll
        for (int j = 0; j < 4; ++j) {
            int col = n_base + j * 16 + (lane & 15);
            #pragma unroll
            for (int t = 0; t < 4; ++t) {
                int rowg = m_base + i * 16 + (lane >> 4) * 4 + t;
                float v = acc[i][j][t] * alpha;
                if (F32OUT) ((float*)Dg)[(long long)zz * sD + (long long)rowg * N + col] = v;
                else        ((bf16*)Dg)[(long long)zz * sD + (long long)rowg * N + col] = (bf16)v;
                if (BNRED) { s_it[i][t] += v; q_it[i][t] += v * v; }
            }
        }
    }

    if (BNRED) {
        #pragma unroll
        for (int i = 0; i < 4; ++i) {
            #pragma unroll
            for (int t = 0; t < 4; ++t) {
                float s = s_it[i][t], q = q_it[i][t];
                #pragma unroll
                for (int m = 1; m < 16; m <<= 1) {
                    s += __shfl_xor(s, m);
                    q += __shfl_xor(q, m);
                }
                if ((lane & 15) == 0) {
                    int cl = wm * 64 + i * 16 + (lane >> 4) * 4 + t;   // 0..127
                    atomicAdd(&bs[cl], s);
                    atomicAdd(&bq[cl], q);
                }
            }
        }
        __syncthreads();
        if (threadIdx.x < 128) {
            int cg = by * 128 + threadIdx.x;
            atomicAdd(&ps[cg], bs[threadIdx.x]);
            atomicAdd(&pq[cg], bq[threadIdx.x]);
        }
    }
}

// ---------------- symmetric GEMM: D = alpha * X X^T, compact upper-tri, z-major XCD ----------------
// Linear dispatch id d = blockIdx.z*171 + blockIdx.x; zz = d % gridDim.z (XCD affinity);
// t = d / gridDim.z in [0,171) decodes to (bi,bj), bj>=bi. Off-diagonal: mirror tile to
// (bj,bi) via LDS transpose (140-stride rows, b64 writes). Diagonal: B aliases A.
__global__ __launch_bounds__(256)
void gemm_sym(const bf16* __restrict__ Xg, bf16* __restrict__ Dg,
              int K, int N, long long sX, long long sD, float alpha)
{
    const int NZ = gridDim.z;
    const int d  = blockIdx.z * 171 + blockIdx.x;
    const int zz = d % NZ;
    int tlin     = d / NZ;                 // 0..170, bijective (171*NZ blocks total)
    int bi = 0;
    while (tlin >= 18 - bi) { tlin -= 18 - bi; ++bi; }
    const int bj = bi + tlin;
    const bool mir  = (bj > bi);
    const bool diag = (bj == bi);

    __shared__ __align__(16) char lds[35840];   // GEMM: A 16K + B 16K; epilogue: 128 x 140 bf16
    char* ldsA = lds;
    char* ldsB = diag ? lds : (lds + 16384);

    const int lane = threadIdx.x & 63;
    const int wv   = threadIdx.x >> 6;
    const int wm   = wv >> 1;
    const int wn   = wv & 1;

    const bf16* Ab = Xg + (long long)zz * sX + (long long)bi * 128 * K;
    const bf16* Bb = Xg + (long long)zz * sX + (long long)bj * 128 * K;

    f32x4 acc[4][4];
    #pragma unroll
    for (int i = 0; i < 4; ++i)
        #pragma unroll
        for (int j = 0; j < 4; ++j) {
            f32x4 z = {0.f, 0.f, 0.f, 0.f};
            acc[i][j] = z;
        }

    for (int k0 = 0; k0 < K; k0 += 64) {
        #pragma unroll
        for (int t = 0; t < 4; ++t) {
            int ch  = (wv * 4 + t) * 64 + lane;   // 0..1023
            int row = ch >> 3;
            int cc  = (ch & 7) ^ (row & 7);
            bf16x8 va = *(const bf16x8*)(Ab + (long long)row * K + k0 + cc * 8);
            *(bf16x8*)(ldsA + ch * 16) = va;
            if (!diag) {
                bf16x8 vb = *(const bf16x8*)(Bb + (long long)row * K + k0 + cc * 8);
                *(bf16x8*)(ldsB + ch * 16) = vb;
            }
        }
        __syncthreads();

        #pragma unroll
        for (int kk = 0; kk < 64; kk += 32) {
            bf16x8 af[4], bfr[4];
            #pragma unroll
            for (int i = 0; i < 4; ++i) {
                int r = wm * 64 + i * 16 + (lane & 15);
                int c = ((kk >> 3) + (lane >> 4)) ^ (r & 7);
                af[i] = *(const bf16x8*)(ldsA + r * 128 + c * 16);
            }
            #pragma unroll
            for (int j = 0; j < 4; ++j) {
                int r = wn * 64 + j * 16 + (lane & 15);
                int c = ((kk >> 3) + (lane >> 4)) ^ (r & 7);
                bfr[j] = *(const bf16x8*)(ldsB + r * 128 + c * 16);
            }
            #pragma unroll
            for (int i = 0; i < 4; ++i)
                #pragma unroll
                for (int j = 0; j < 4; ++j)
                    acc[i][j] = __builtin_amdgcn_mfma_f32_16x16x32_bf16(af[i], bfr[j], acc[i][j], 0, 0, 0);
        }
        __syncthreads();
    }

    bf16* Db = Dg + (long long)zz * sD;
    bf16 (*tr)[140] = (bf16(*)[140])lds;   // k-loop ended with a barrier; LDS free

    #pragma unroll
    for (int i = 0; i < 4; ++i) {
        #pragma unroll
        for (int j = 0; j < 4; ++j) {
            int c_loc = wn * 64 + j * 16 + (lane & 15);
            int col   = bj * 128 + c_loc;
            bf16x4 tv;
            #pragma unroll
            for (int t = 0; t < 4; ++t) {
                int r_loc = wm * 64 + i * 16 + (lane >> 4) * 4 + t;
                float v = acc[i][j][t] * alpha;
                Db[(long long)(bi * 128 + r_loc) * N + col] = (bf16)v;
                tv[t] = (bf16)v;
            }
            if (mir) {
                int r_base = wm * 64 + i * 16 + (lane >> 4) * 4;   // 8B-aligned in tr row
                *(bf16x4*)(&tr[c_loc][r_base]) = tv;               // one ds_write_b64
            }
        }
    }

    if (mir) {
        __syncthreads();
        // 256 threads x 64 bf16: thread (cc=tid>>1, hf=tid&1) copies half a transposed row.
        const int cc = threadIdx.x >> 1, hf = threadIdx.x & 1;
        const bf16* src = &tr[cc][hf * 64];
        bf16* dst = Db + (long long)(bj * 128 + cc) * N + bi * 128 + hf * 64;
        #pragma unroll
        for (int j2 = 0; j2 < 8; ++j2)
            *(bf16x8*)(dst + j2 * 8) = *(const bf16x8*)(src + j2 * 8);
    }
}

// ---------------- f32 -> bf16 bulk convert (weights) ----------------
__global__ __launch_bounds__(256)
void f32_to_bf16(const float* __restrict__ in, bf16* __restrict__ out, int n)
{
    int idx = (blockIdx.x * 256 + threadIdx.x) * 4;
    if (idx < n) {
        float4 v = *(const float4*)(in + idx);
        out[idx + 0] = (bf16)v.x;
        out[idx + 1] = (bf16)v.y;
        out[idx + 2] = (bf16)v.z;
        out[idx + 3] = (bf16)v.w;
    }
}

// ---------------- zero-init BN accumulators (ws is poisoned 0xAA every launch) ----------------
__global__ __launch_bounds__(256)
void zero_f32(float* __restrict__ p)
{
    p[blockIdx.x * 256 + threadIdx.x] = 0.f;
}

// ---------------- batched transpose x[z][C][N] (f32) -> xT[z][N][C] (bf16) ----------------
__global__ __launch_bounds__(256)
void transpose_f32_bf16(const float* __restrict__ x, bf16* __restrict__ xT)
{
    __shared__ bf16 tile[32][33];
    const float* xb = x + (long long)blockIdx.z * 1024 * 2304;
    bf16* xo = xT + (long long)blockIdx.z * 2304 * 1024;
    const int n0 = blockIdx.x * 32;
    const int c0 = blockIdx.y * 32;
    const int tx = threadIdx.x, ty = threadIdx.y;   // (32, 8)
    #pragma unroll
    for (int i = 0; i < 32; i += 8)
        tile[ty + i][tx] = (bf16)xb[(long long)(c0 + ty + i) * 2304 + n0 + tx];
    __syncthreads();
    #pragma unroll
    for (int i = 0; i < 32; i += 8)
        xo[(long long)(n0 + ty + i) * 1024 + c0 + tx] = tile[tx][ty + i];
}

// ---------------- register-resident row softmax (N=2304), one block per row ----------------
__global__ __launch_bounds__(256)
void softmax_rows(bf16* __restrict__ S)
{
    bf16* p = S + (long long)blockIdx.x * 2304;
    const int t = threadIdx.x;
    __shared__ float red[256];

    bf16x8 v8 = *(const bf16x8*)(p + t * 8);
    float vt = (float)p[2048 + t];
    float f[8];
    float mx = vt;
    #pragma unroll
    for (int i = 0; i < 8; ++i) { f[i] = (float)v8[i]; mx = fmaxf(mx, f[i]); }

    red[t] = mx; __syncthreads();
    for (int s = 128; s > 0; s >>= 1) { if (t < s) red[t] = fmaxf(red[t], red[t + s]); __syncthreads(); }
    mx = red[0];
    __syncthreads();

    float sum = 0.f;
    #pragma unroll
    for (int i = 0; i < 8; ++i) { f[i] = __expf(f[i] - mx); sum += f[i]; }
    vt = __expf(vt - mx); sum += vt;

    red[t] = sum; __syncthreads();
    for (int s = 128; s > 0; s >>= 1) { if (t < s) red[t] += red[t + s]; __syncthreads(); }
    float inv = 1.0f / red[0];

    bf16x8 o;
    #pragma unroll
    for (int i = 0; i < 8; ++i) o[i] = (bf16)(f[i] * inv);
    *(bf16x8*)(p + t * 8) = o;
    p[2048 + t] = (bf16)(vt * inv);
}

// ---------------- BN finalize: psum/pqsm already summed over all batches ----------------
__global__ __launch_bounds__(256)
void bn_finalize(const float* __restrict__ ps, const float* __restrict__ pq,
                 float* __restrict__ mean, float* __restrict__ istd)
{
    int c = blockIdx.x * 256 + threadIdx.x;   // grid 4 x 256 = 1024
    float mu = ps[c] / 18432.0f;
    mean[c] = mu;
    istd[c] = rsqrtf(pq[c] / 18432.0f - mu * mu + 1e-5f);
}

// ---------------- BN apply + residual: wy in bf16, x/z f32 ----------------
__global__ __launch_bounds__(256)
void bn_apply_b(const bf16* __restrict__ wy, const float* __restrict__ x,
                const float* __restrict__ gamma, const float* __restrict__ beta,
                const float* __restrict__ mean, const float* __restrict__ istd,
                float* __restrict__ z)
{
    long long idx = ((long long)blockIdx.x * 256 + threadIdx.x) * 8;
    int c = (int)((idx / 2304) & 1023);    // layout [B][C][N], N divisible by 8
    float sc = gamma[c] * istd[c];
    float sh = beta[c] - mean[c] * sc;
    bf16x8 w  = *(const bf16x8*)(wy + idx);
    float4 x0 = *(const float4*)(x + idx);
    float4 x1 = *(const float4*)(x + idx + 4);
    float4 o0, o1;
    o0.x = (float)w[0] * sc + sh + x0.x;
    o0.y = (float)w[1] * sc + sh + x0.y;
    o0.z = (float)w[2] * sc + sh + x0.z;
    o0.w = (float)w[3] * sc + sh + x0.w;
    o1.x = (float)w[4] * sc + sh + x1.x;
    o1.y = (float)w[5] * sc + sh + x1.y;
    o1.z = (float)w[6] * sc + sh + x1.z;
    o1.w = (float)w[7] * sc + sh + x1.w;
    *(float4*)(z + idx)     = o0;
    *(float4*)(z + idx + 4) = o1;
}

extern "C" void kernel_launch(void* const* d_in, const int* in_sizes, int n_in,
                              void* d_out, int out_size, void* d_ws, size_t ws_size,
                              hipStream_t stream)
{
    const float* x     = (const float*)d_in[0];
    const float* Wg    = (const float*)d_in[1];
    const float* Wz    = (const float*)d_in[2];
    const float* gamma = (const float*)d_in[3];
    const float* beta  = (const float*)d_in[4];
    float* zo = (float*)d_out;

    const int B = 8, C = 1024, Cb = 512, N = 2304;

    // ws-adaptive batch chunking: BC in {8,4,2,1}, largest whose footprint fits.
    const size_t fixedB = ((size_t)Cb * C * 2) * 2 + (size_t)C * 4 * 4 + 4096;
    const size_t perB   = ((size_t)N * C + (size_t)Cb * N + (size_t)N * N + (size_t)N * Cb
                           + (size_t)C * N) * 2 + 1280;
    int BC = 8;
    while (BC > 1 && fixedB + perB * (size_t)BC > ws_size) BC >>= 1;

    char* p = (char*)d_ws;
    auto alloc = [&](size_t bytes) { char* r = p; p += (bytes + 255) & ~(size_t)255; return r; };
    bf16*  Wgb  = (bf16*)alloc((size_t)Cb * C * 2);
    bf16*  Wzb  = (bf16*)alloc((size_t)C * Cb * 2);
    float* psum = (float*)alloc((size_t)C * 4);   // contiguous with pqsm (both 4 KB)
    float* pqsm = (float*)alloc((size_t)C * 4);
    float* mean = (float*)alloc((size_t)C * 4);
    float* istd = (float*)alloc((size_t)C * 4);
    bf16*  xT   = (bf16*)alloc((size_t)BC * N * C * 2);
    bf16*  g    = (bf16*)alloc((size_t)BC * Cb * N * 2);
    bf16*  attn = (bf16*)alloc((size_t)BC * N * N * 2);
    bf16*  yT   = (bf16*)alloc((size_t)BC * N * Cb * 2);
    bf16*  wyb  = (bf16*)alloc((size_t)BC * C * N * 2);

    // 0) weights f32 -> bf16; zero BN accumulators (psum+pqsm contiguous, 2048 floats)
    f32_to_bf16<<<dim3((Cb * C) / (256 * 4)), 256, 0, stream>>>(Wg, Wgb, Cb * C);
    f32_to_bf16<<<dim3((C * Cb) / (256 * 4)), 256, 0, stream>>>(Wz, Wzb, C * Cb);
    zero_f32<<<dim3(8), 256, 0, stream>>>(psum);

    for (int cs = 0; cs < B; cs += BC) {
        const float* xc = x + (long long)cs * C * N;

        // xT[z][n][c] = x[cs+z][c][n] (bf16)
        transpose_f32_bf16<<<dim3(N / 32, C / 32, BC), dim3(32, 8), 0, stream>>>(xc, xT);

        // g[z][d][n] = sum_c Wgb[d][c] * xT[z][n][c]   (M=512, N=2304, K=1024)
        // z-affinity; by inner (4 d-blocks share each xT n-tile; xT[z] hot in its XCD L2)
        gemm_btz<false, false, false><<<dim3(18 * 4 * BC), 256, 0, stream>>>(
            Wgb, xT, g, C, N, 0, (long long)N * C, (long long)Cb * N, 1.0f,
            nullptr, nullptr, 4, BC);

        // attn[z][n][m] = sum_c xT[z][n][c]*xT[z][m][c] / 2304  (M=N=2304, K=1024)
        // symmetric: compact triangular launch (171 live blocks/z), z-major XCD affinity
        gemm_sym<<<dim3(171, 1, BC), 256, 0, stream>>>(
            xT, attn, C, N, (long long)N * C, (long long)N * N, 1.0f / 2304.0f);

        // row softmax, one read one write
        softmax_rows<<<dim3(BC * N), 256, 0, stream>>>(attn);

        // yT[z][n][d] = sum_m attn[z][n][m] * g[z][d][m]  (M=2304, N=512, K=2304)
        // z-affinity; bx inner (4 d-blocks share each attn row-tile; g[z] 2.36MB resident)
        gemm_btz<false, false, true><<<dim3(4 * 18 * BC), 256, 0, stream>>>(
            attn, g, yT, N, Cb, (long long)N * N, (long long)Cb * N, (long long)N * Cb, 1.0f,
            nullptr, nullptr, 4, BC);

        // wy[z][c][n] = sum_d Wzb[c][d] * yT[z][n][d]  (M=1024, N=2304, K=512)
        // -> bf16 into wyb, fused BN sum/sumsq (f32). z-affinity; by inner (8 c-blocks
        // share each yT n-tile; yT[z] 2.36MB resident).
        gemm_btz<false, true, false><<<dim3(18 * 8 * BC), 256, 0, stream>>>(
            Wzb, yT, wyb + (long long)0, Cb, N, 0, (long long)N * Cb, (long long)C * N, 1.0f,
            psum, pqsm, 8, BC);

        // BN apply + residual for this chunk cannot run yet (stats global) -- see below.
        // wyb is per-chunk; with BC==8 single pass. For BC<8 we must keep wy of all
        // chunks: fall back to writing into distinct wyb slices only when BC==B.
        // (ws sizing keeps BC==8 when possible; if BC<8, reuse wyb per chunk and apply
        // BN per chunk AFTER the loop would be wrong -> handle by storing per-chunk
        // slices: wyb holds BC z's; we copy nothing extra since bn_apply runs after the
        // full loop only when BC==B. For BC<B, run bn_apply per chunk after finalize
        // is impossible; instead we accept BC<8 path writing wyb chunk-local and
        // bn_apply reading it chunk-local after a second mini-loop (see below).
    }

    // BN: finalize -> apply (+residual)
    bn_finalize<<<dim3(C / 256), 256, 0, stream>>>(psum, pqsm, mean, istd);

    if (BC == B) {
        bn_apply_b<<<dim3((B * C * N) / (256 * 8)), 256, 0, stream>>>(
            wyb, x, gamma, beta, mean, istd, zo);
    } else {
        // BC<8: wyb only holds the LAST chunk's wy. Recompute wy per chunk (stats are
        // final now) and apply. This path trades extra GEMM time for correctness and
        // only triggers on small-ws configurations.
        for (int cs = 0; cs < B; cs += BC) {
            const float* xc = x + (long long)cs * C * N;
            float* zoc = zo + (long long)cs * C * N;
            transpose_f32_bf16<<<dim3(N / 32, C / 32, BC), dim3(32, 8), 0, stream>>>(xc, xT);
            gemm_btz<false, false, false><<<dim3(18 * 4 * BC), 256, 0, stream>>>(
                Wgb, xT, g, C, N, 0, (long long)N * C, (long long)Cb * N, 1.0f,
                nullptr, nullptr, 4, BC);
            gemm_sym<<<dim3(171, 1, BC), 256, 0, stream>>>(
                xT, attn, C, N, (long long)N * C, (long long)N * N, 1.0f / 2304.0f);
            softmax_rows<<<dim3(BC * N), 256, 0, stream>>>(attn);
            gemm_btz<false, false, true><<<dim3(4 * 18 * BC), 256, 0, stream>>>(
                attn, g, yT, N, Cb, (long long)N * N, (long long)Cb * N, (long long)N * Cb,
                1.0f, nullptr, nullptr, 4, BC);
            gemm_btz<false, false, false><<<dim3(18 * 8 * BC), 256, 0, stream>>>(
                Wzb, yT, wyb, Cb, N, 0, (long long)N * Cb, (long long)C * N, 1.0f,
                nullptr, nullptr, 8, BC);
            bn_apply_b<<<dim3((BC * C * N) / (256 * 8)), 256, 0, stream>>>(
                wyb, xc, gamma, beta, mean, istd, zoc);
        }
    }
}